// Round 2
// baseline (14131.148 us; speedup 1.0000x reference)
//
#include <hip/hip_runtime.h>
#include <hip/hip_bf16.h>
#include <math.h>

typedef __hip_bfloat16 bf16;

#define B_N 32
#define S_N 512
#define D_N 1024
#define H_N 1024
#define HH_N 512
#define EPS_F 1e-6f

static __device__ __forceinline__ float b2f(bf16 v){ return __bfloat162float(v); }
static __device__ __forceinline__ bf16 f2b(float v){ return __float2bfloat16(v); }

struct b4s { bf16 v[4]; };

template<typename T> struct TIO;
template<> struct TIO<float>{
  static __device__ __forceinline__ float ld(const float* p){ return *p; }
  static __device__ __forceinline__ void st(float* p, float v){ *p = v; }
  static __device__ __forceinline__ void ld4(const float* p, float* o){
    float4 x = *reinterpret_cast<const float4*>(p);
    o[0]=x.x; o[1]=x.y; o[2]=x.z; o[3]=x.w; }
};
template<> struct TIO<bf16>{
  static __device__ __forceinline__ float ld(const bf16* p){ return b2f(*p); }
  static __device__ __forceinline__ void st(bf16* p, float v){ *p = f2b(v); }
  static __device__ __forceinline__ void ld4(const bf16* p, float* o){
    b4s x = *reinterpret_cast<const b4s*>(p);
    o[0]=b2f(x.v[0]); o[1]=b2f(x.v[1]); o[2]=b2f(x.v[2]); o[3]=b2f(x.v[3]); }
};

// ---------------- dtype probe -------------------------------------------------
// Read W_h (n elements) as bf16. Real data |v| <= ~8; fp32-as-bf16 low halves
// are uniform bits -> many exponents >= 140 (|v| >= 2^13). bad>0 => fp32.
__global__ __launch_bounds__(256) void k_probe(const unsigned short* __restrict__ w,
                                               int n, int* __restrict__ bad){
  int stride = gridDim.x*256;
  int bd = 0;
  for(int j = blockIdx.x*256 + threadIdx.x; j < n; j += stride){
    unsigned short u = w[j];
    int e = (u >> 7) & 0xFF;
    if(e >= 140) bd = 1;
  }
  if(bd) atomicAdd(bad, 1);
}

// ---------------- transpose: dst[c][k] = src[k][c], 1024x1024 -> f32 ----------
template<typename TI>
__device__ __forceinline__ void transpose_impl(const TI* __restrict__ src,
                                               float* __restrict__ dst,
                                               float (*tile)[33]){
  int c0 = blockIdx.x*32, k0 = blockIdx.y*32;
  int tx = threadIdx.x & 31, ty = threadIdx.x >> 5;   // 32 x 8
  for(int i=ty;i<32;i+=8) tile[i][tx] = TIO<TI>::ld(src + (size_t)(k0+i)*H_N + c0 + tx);
  __syncthreads();
  for(int i=ty;i<32;i+=8) dst[(size_t)(c0+i)*H_N + k0 + tx] = tile[tx][i];
}
__global__ __launch_bounds__(256) void k_transpose(const void* __restrict__ src,
                                                   size_t eoff, float* __restrict__ dst,
                                                   const int* __restrict__ bad){
  __shared__ float tile[32][33];
  if(*bad == 0) transpose_impl<bf16>((const bf16*)src + eoff, dst, tile);
  else          transpose_impl<float>((const float*)src + eoff, dst, tile);
}

// ---------------- precompute: xp=tanh(x@W_x+b_x), xr=x@W_r[:D] (bf16 out) -----
template<typename TI>
__device__ __forceinline__ void precompute_impl(
    const TI* __restrict__ x, const TI* __restrict__ Wx, const TI* __restrict__ Wr,
    const TI* __restrict__ bx, bf16* __restrict__ xp, bf16* __restrict__ xr,
    float (*a_s)[65], float (*b_s)[65])
{
  int m0 = blockIdx.y*64, n0 = blockIdx.x*64;
  bool isR = (n0 >= H_N);
  const TI* Bm = isR ? Wr : Wx;
  int nb = isR ? (n0 - H_N) : n0;
  int tid = threadIdx.x, tx = tid & 15, ty = tid >> 4;
  int amm = tid & 63, akk = (tid >> 6) << 2;
  int am = m0 + amm; int ab = am & (B_N-1), at = am >> 5;   // m = t*B + b
  const TI* arow = x + ((size_t)ab*S_N + at)*D_N;
  int bkk = tid >> 4, bnn = (tid & 15) << 2;
  float acc[4][4] = {};
  for(int k0=0;k0<D_N;k0+=16){
    float av[4]; TIO<TI>::ld4(arow + k0 + akk, av);
    float bv[4]; TIO<TI>::ld4(Bm + (size_t)(k0+bkk)*H_N + nb + bnn, bv);
    __syncthreads();
    a_s[akk+0][amm]=av[0]; a_s[akk+1][amm]=av[1]; a_s[akk+2][amm]=av[2]; a_s[akk+3][amm]=av[3];
    b_s[bkk][bnn+0]=bv[0]; b_s[bkk][bnn+1]=bv[1]; b_s[bkk][bnn+2]=bv[2]; b_s[bkk][bnn+3]=bv[3];
    __syncthreads();
    #pragma unroll
    for(int kk=0;kk<16;kk++){
      float ar[4], br[4];
      #pragma unroll
      for(int i=0;i<4;i++) ar[i]=a_s[kk][ty*4+i];
      #pragma unroll
      for(int j=0;j<4;j++) br[j]=b_s[kk][tx*4+j];
      #pragma unroll
      for(int i=0;i<4;i++)
        #pragma unroll
        for(int j=0;j<4;j++) acc[i][j] += ar[i]*br[j];
    }
  }
  for(int i=0;i<4;i++){
    int m = m0 + ty*4 + i;
    size_t rowoff = (size_t)m*H_N;
    for(int j=0;j<4;j++){
      int n = nb + tx*4 + j;
      float v = acc[i][j];
      if(!isR){ v = tanhf(v + TIO<TI>::ld(bx + n)); xp[rowoff + n] = f2b(v); }
      else    { xr[rowoff + n] = f2b(v); }
    }
  }
}
__global__ __launch_bounds__(256) void k_precompute(
    const void* x, const void* Wx, const void* Wr, const void* bx,
    bf16* xp, bf16* xr, const int* __restrict__ bad)
{
  __shared__ float a_s[16][65];
  __shared__ float b_s[16][65];
  if(*bad == 0) precompute_impl<bf16>((const bf16*)x,(const bf16*)Wx,(const bf16*)Wr,
                                      (const bf16*)bx, xp, xr, a_s, b_s);
  else          precompute_impl<float>((const float*)x,(const float*)Wx,(const float*)Wr,
                                       (const float*)bx, xp, xr, a_s, b_s);
}

// ---------------- one recurrence step ----------------------------------------
__global__ __launch_bounds__(256) void k_step(
    const float* __restrict__ h_cur, float* __restrict__ h_nxt,
    bf16* __restrict__ h_all_t, const bf16* __restrict__ xp_t, const bf16* __restrict__ xr_t,
    const float* __restrict__ WhT, const float* __restrict__ WrT,
    const void* __restrict__ b_h_v, const void* __restrict__ b_r_v,
    const void* __restrict__ W_s_v, const void* __restrict__ b_s_v,
    const void* __restrict__ mob_a_v, const void* __restrict__ mob_b_v,
    const void* __restrict__ mob_c_v, const void* __restrict__ mob_d_v,
    const int* __restrict__ bad)
{
  __shared__ float hs[32][260];        // pad: stride%32==4 -> ~4-way not 32-way
  __shared__ float wsl[1024*3];
  __shared__ float spart[32][8][3];
  __shared__ float sbar[32];
  __shared__ float val[8][32];
  int tid = threadIdx.x;
  int bid = blockIdx.x;
  bool isbf = (*bad == 0);
  auto dld = [&](const void* p, int i)->float{
    return isbf ? b2f(((const bf16*)p)[i]) : ((const float*)p)[i];
  };

  for(int i=tid;i<1024*3;i+=256) wsl[i] = dld(W_s_v, i);
  __syncthreads();

  // s-phase: logits = h_row @ W_s
  {
    int row = tid>>3, seg = tid&7;
    const float* hr = h_cur + (size_t)row*H_N + seg*128;
    float p0=0.f,p1=0.f,p2=0.f;
    for(int j=0;j<128;j+=4){
      float4 hv = *reinterpret_cast<const float4*>(hr+j);
      int kb = (seg*128 + j)*3;
      p0 += hv.x*wsl[kb+0] + hv.y*wsl[kb+3] + hv.z*wsl[kb+6] + hv.w*wsl[kb+9];
      p1 += hv.x*wsl[kb+1] + hv.y*wsl[kb+4] + hv.z*wsl[kb+7] + hv.w*wsl[kb+10];
      p2 += hv.x*wsl[kb+2] + hv.y*wsl[kb+5] + hv.z*wsl[kb+8] + hv.w*wsl[kb+11];
    }
    spart[row][seg][0]=p0; spart[row][seg][1]=p1; spart[row][seg][2]=p2;
  }
  __syncthreads();
  if(tid<32){
    float l0=dld(b_s_v,0), l1=dld(b_s_v,1), l2=dld(b_s_v,2);
    for(int s=0;s<8;s++){ l0+=spart[tid][s][0]; l1+=spart[tid][s][1]; l2+=spart[tid][s][2]; }
    float mx = fmaxf(l0,fmaxf(l1,l2));
    float e0=expf(l0-mx), e1=expf(l1-mx), e2=expf(l2-mx);
    float inv = 1.f/(e0+e1+e2);
    sbar[tid] = (e0 + 0.5f*e1 + 0.25f*e2)*inv;
  }

  // main dots: thread (row, c): c: isR=c>>2, cc=c&3, hi=cc>>1, ps=cc&1
  int row = tid & 31, c = tid >> 5;
  int isR = c >> 2, cc = c & 3, hi = cc >> 1, ps = cc & 1;
  int pair = 2*bid + ps;
  int col  = pair + hi*HH_N;
  const float* WT = (isR ? WrT : WhT) + (size_t)col*H_N;
  float acc = 0.f;
  for(int kc=0;kc<4;kc++){
    int k0 = kc*256;
    __syncthreads();
    #pragma unroll
    for(int u=0;u<8;u++){
      int lin = tid + u*256;            // float4 idx 0..2047 (32 rows x 64)
      int b = lin >> 6, j = lin & 63;
      *reinterpret_cast<float4*>(&hs[b][j<<2]) =
        reinterpret_cast<const float4*>(h_cur)[b*256 + (k0>>2) + j];
    }
    __syncthreads();
    const float* hp = &hs[row][0];
    const float* wp = WT + k0;
    #pragma unroll 8
    for(int j=0;j<256;j+=4){
      float4 hv = *reinterpret_cast<const float4*>(hp+j);
      float4 wv = *reinterpret_cast<const float4*>(wp+j);
      acc += hv.x*wv.x + hv.y*wv.y + hv.z*wv.z + hv.w*wv.w;
    }
  }
  float v;
  if(!isR){
    float xin = b2f(xp_t[(size_t)row*H_N + col]);
    v = tanhf(acc + xin + dld(b_h_v, col));
  }else{
    float xin = b2f(xr_t[(size_t)row*H_N + col]);
    float tpre = acc + xin + dld(b_r_v, col);
    v = 1.f/(1.f + expf(-tpre));
  }
  val[c][row] = v;
  __syncthreads();

  if(tid < 64){
    int row2 = tid & 31, ps2 = tid >> 5;
    int p = 2*bid + ps2;
    float zo = val[0+ps2][row2];
    float zp = val[2+ps2][row2];
    float ro = val[4+ps2][row2];
    float rp = val[6+ps2][row2];
    #pragma unroll
    for(int k=0;k<3;k++){
      float are=dld(mob_a_v,(k*2+0)*HH_N+p), aim=dld(mob_a_v,(k*2+1)*HH_N+p);
      float bre=dld(mob_b_v,(k*2+0)*HH_N+p), bim=dld(mob_b_v,(k*2+1)*HH_N+p);
      float cre=dld(mob_c_v,(k*2+0)*HH_N+p), cim=dld(mob_c_v,(k*2+1)*HH_N+p);
      float dre=dld(mob_d_v,(k*2+0)*HH_N+p), dim_=dld(mob_d_v,(k*2+1)*HH_N+p);
      float nre = are*zo - aim*zp + bre;
      float nim = are*zp + aim*zo + bim;
      float de  = cre*zo - cim*zp + dre;
      float di  = cre*zp + cim*zo + dim_;
      float d2  = de*de + di*di + EPS_F;
      float inv = 1.f/d2;
      float nzo = (nre*de + nim*di)*inv;
      float nzp = (nim*de - nre*di)*inv;
      zo = nzo; zp = nzp;
    }
    float sb = sbar[row2];
    ro *= sb; rp *= sb;
    float ho  = h_cur[(size_t)row2*H_N + p];
    float hp2 = h_cur[(size_t)row2*H_N + p + HH_N];
    float no  = (1.f-ro)*ho + ro*zo;
    float np2 = (1.f-rp)*hp2 + rp*zp;
    h_nxt[(size_t)row2*H_N + p] = no;
    h_nxt[(size_t)row2*H_N + p + HH_N] = np2;
    h_all_t[(size_t)row2*H_N + p] = f2b(no);
    h_all_t[(size_t)row2*H_N + p + HH_N] = f2b(np2);
  }
}

// ---------------- final: out[b][t][:] = tanh(hall[t][b][:] @ W_o + b_o) ------
template<typename TI>
__device__ __forceinline__ void final_impl(
    const bf16* __restrict__ hall, const TI* __restrict__ Wo,
    const TI* __restrict__ bo, TI* __restrict__ out,
    float (*a_s)[65], float (*b_s)[65])
{
  int m0 = blockIdx.y*64, n0 = blockIdx.x*64;
  int tid = threadIdx.x, tx = tid & 15, ty = tid >> 4;
  int amm = tid & 63, akk = (tid >> 6) << 2;
  const bf16* arow = hall + (size_t)(m0+amm)*H_N;
  int bkk = tid >> 4, bnn = (tid & 15) << 2;
  float acc[4][4] = {};
  for(int k0=0;k0<H_N;k0+=16){
    float av[4]; TIO<bf16>::ld4(arow + k0 + akk, av);
    float bv[4]; TIO<TI>::ld4(Wo + (size_t)(k0+bkk)*H_N + n0 + bnn, bv);
    __syncthreads();
    a_s[akk+0][amm]=av[0]; a_s[akk+1][amm]=av[1]; a_s[akk+2][amm]=av[2]; a_s[akk+3][amm]=av[3];
    b_s[bkk][bnn+0]=bv[0]; b_s[bkk][bnn+1]=bv[1]; b_s[bkk][bnn+2]=bv[2]; b_s[bkk][bnn+3]=bv[3];
    __syncthreads();
    #pragma unroll
    for(int kk=0;kk<16;kk++){
      float ar[4], br[4];
      #pragma unroll
      for(int i=0;i<4;i++) ar[i]=a_s[kk][ty*4+i];
      #pragma unroll
      for(int j=0;j<4;j++) br[j]=b_s[kk][tx*4+j];
      #pragma unroll
      for(int i=0;i<4;i++)
        #pragma unroll
        for(int j=0;j<4;j++) acc[i][j] += ar[i]*br[j];
    }
  }
  for(int i=0;i<4;i++){
    int m = m0 + ty*4 + i;
    int b = m & (B_N-1), t = m >> 5;
    size_t orow = ((size_t)b*S_N + t)*H_N;
    for(int j=0;j<4;j++){
      int n = n0 + tx*4 + j;
      TIO<TI>::st(out + orow + n, tanhf(acc[i][j] + TIO<TI>::ld(bo + n)));
    }
  }
}
__global__ __launch_bounds__(256) void k_final(
    const bf16* hall, const void* Wo, const void* bo, void* out, const int* __restrict__ bad)
{
  __shared__ float a_s[16][65];
  __shared__ float b_s[16][65];
  if(*bad == 0) final_impl<bf16>(hall,(const bf16*)Wo,(const bf16*)bo,(bf16*)out,a_s,b_s);
  else          final_impl<float>(hall,(const float*)Wo,(const float*)bo,(float*)out,a_s,b_s);
}

// ---------------- tail: of/pf from hall[S-1] ---------------------------------
__global__ __launch_bounds__(256) void k_tail(const bf16* __restrict__ hlast,
                                              void* __restrict__ out,
                                              const int* __restrict__ bad){
  int i = blockIdx.x*256 + threadIdx.x;   // 0..B*H-1
  int b = i >> 10, cidx = i & 1023;
  float v = b2f(hlast[(size_t)b*H_N + cidx]);
  size_t base = (size_t)B_N*S_N*H_N;
  size_t idx;
  if(cidx < HH_N) idx = base + (size_t)b*HH_N + cidx;
  else            idx = base + (size_t)B_N*HH_N + (size_t)b*HH_N + (cidx-HH_N);
  if(*bad == 0) ((bf16*)out)[idx] = f2b(v);
  else          ((float*)out)[idx] = v;
}

// ---------------- host --------------------------------------------------------
extern "C" void kernel_launch(void* const* d_in, const int* in_sizes, int n_in,
                              void* d_out, int out_size, void* d_ws, size_t ws_size,
                              hipStream_t stream)
{
  const void* x    = d_in[0];
  const void* W_x  = d_in[1];
  const void* b_x  = d_in[2];
  const void* W_h  = d_in[3];
  const void* b_h  = d_in[4];
  const void* W_r  = d_in[5];
  const void* b_r  = d_in[6];
  const void* W_s  = d_in[7];
  const void* b_s  = d_in[8];
  const void* mob_a= d_in[9];
  const void* mob_b= d_in[10];
  const void* mob_c= d_in[11];
  const void* mob_d= d_in[12];
  const void* W_o  = d_in[13];
  const void* b_o  = d_in[14];

  char* ws = (char*)d_ws;
  size_t off = 0;
  auto carve = [&](size_t bytes)->char*{
    char* p = ws + off; off = (off + bytes + 255) & ~(size_t)255; return p;
  };
  int*   bad = (int*)carve(sizeof(int));
  float* WhT = (float*)carve((size_t)H_N*H_N*sizeof(float));
  float* WrT = (float*)carve((size_t)H_N*H_N*sizeof(float));
  float* hb0 = (float*)carve((size_t)B_N*H_N*sizeof(float));
  float* hb1 = (float*)carve((size_t)B_N*H_N*sizeof(float));
  size_t bigN = (size_t)S_N*B_N*H_N;
  bf16* xp   = (bf16*)carve(bigN*sizeof(bf16));
  bf16* xr   = (bf16*)carve(bigN*sizeof(bf16));
  bf16* hall = (bf16*)carve(bigN*sizeof(bf16));

  (void)hipMemsetAsync(bad, 0, sizeof(int), stream);
  k_probe<<<256,256,0,stream>>>((const unsigned short*)W_h, in_sizes[3], bad);

  k_transpose<<<dim3(32,32),256,0,stream>>>(W_h, 0, WhT, bad);
  k_transpose<<<dim3(32,32),256,0,stream>>>(W_r, (size_t)D_N*H_N, WrT, bad);
  k_precompute<<<dim3(32,256),256,0,stream>>>(x, W_x, W_r, b_x, xp, xr, bad);

  (void)hipMemsetAsync(hb0, 0, (size_t)B_N*H_N*sizeof(float), stream);
  float* hc = hb0; float* hn = hb1;
  for(int t=0;t<S_N;t++){
    k_step<<<256,256,0,stream>>>(hc, hn,
        hall + (size_t)t*B_N*H_N, xp + (size_t)t*B_N*H_N, xr + (size_t)t*B_N*H_N,
        WhT, WrT, b_h, b_r, W_s, b_s, mob_a, mob_b, mob_c, mob_d, bad);
    float* tmp = hc; hc = hn; hn = tmp;
  }
  k_final<<<dim3(16,256),256,0,stream>>>(hall, W_o, b_o, d_out, bad);
  k_tail<<<dim3(128),256,0,stream>>>(hall + (size_t)(S_N-1)*B_N*H_N, d_out, bad);
}

// Round 7
// 9297.362 us; speedup vs baseline: 1.5199x; 1.5199x over previous
//
#include <hip/hip_runtime.h>
#include <math.h>

typedef unsigned short u16;
typedef __attribute__((ext_vector_type(8))) short bf16x8;   // 8 bf16 lanes = 4 VGPR
typedef __attribute__((ext_vector_type(4))) float f32x4;

#define B_N 32
#define S_N 512
#define H_N 1024
#define HH_N 512
#define FRAME (B_N*H_N)        /* 32768 elems */
#define EPS_F 1e-6f

#define MFMA16(a,b,c) __builtin_amdgcn_mfma_f32_16x16x32_bf16((a),(b),(c),0,0,0)

static __device__ __forceinline__ u16 f2bu(float v){      // fp32 -> bf16 bits (RNE)
  union{float f; unsigned u;} x; x.f = v;
  unsigned r = x.u + 0x7FFFu + ((x.u>>16)&1u);
  return (u16)(r>>16);
}
static __device__ __forceinline__ float bu2f(u16 s){
  union{unsigned u; float f;} x; x.u = ((unsigned)s)<<16; return x.f;
}
static __device__ __forceinline__ bf16x8 ld8(const u16* p){
  return *reinterpret_cast<const bf16x8*>(p);
}
static __device__ __forceinline__ void cvt8(const float* p, bf16x8& hi, bf16x8& lo){
  #pragma unroll
  for(int j=0;j<8;j++){
    float v = p[j];
    u16 h = f2bu(v);
    hi[j] = (short)h;
    lo[j] = (short)f2bu(v - bu2f(h));
  }
}

// ---------- fp32 1024x1024 transpose+convert: dst[c][k] = bf16(src[k][c]) ----
__global__ __launch_bounds__(256) void k_trcvt(const float* __restrict__ src,
    u16* __restrict__ dh, u16* __restrict__ dl){
  __shared__ float tile[32][33];
  int c0 = blockIdx.x*32, k0 = blockIdx.y*32;
  int tx = threadIdx.x & 31, ty = threadIdx.x >> 5;
  for(int i=ty;i<32;i+=8) tile[i][tx] = src[(size_t)(k0+i)*H_N + c0 + tx];
  __syncthreads();
  for(int i=ty;i<32;i+=8){
    float v = tile[tx][i];
    u16 h = f2bu(v);
    dh[(size_t)(c0+i)*H_N + k0 + tx] = h;
    if(dl) dl[(size_t)(c0+i)*H_N + k0 + tx] = f2bu(v - bu2f(h));
  }
}

// ---------- W_s padded fragment pack (hi only) --------------------------------
// wsp[ks*512 + l*8 + j] = W_s[k = ks*32+(l>>4)*8+j][col = l&15], col>=3 -> 0
__global__ __launch_bounds__(256) void k_wspack(const float* __restrict__ Ws,
                                                u16* __restrict__ wsp){
  int gid = blockIdx.x*256 + threadIdx.x;        // 0..16383
  int j = gid & 7, l = (gid>>3) & 63, ks = gid >> 9;
  int lr = l & 15, lg = l >> 4;
  int k = ks*32 + lg*8 + j;
  wsp[gid] = (lr < 3) ? f2bu(Ws[k*3 + lr]) : (u16)0;
}

// ---------- precompute: xp = tanh(x@W_x+b_x), xr = x@W_r[:D] -----------------
// A (x) converted hi/lo on the fly; B split hi/lo; 3-term MFMA.
__global__ __launch_bounds__(256) void k_pre(const float* __restrict__ x,
    const u16* __restrict__ WxTh, const u16* __restrict__ WxTl,
    const u16* __restrict__ WrxTh, const u16* __restrict__ WrxTl,
    const float* __restrict__ b_x,
    u16* __restrict__ xp, u16* __restrict__ xplo,
    u16* __restrict__ xr, u16* __restrict__ xrlo){
  int tid = threadIdx.x, l = tid&63, wid = tid>>6;
  int wm = wid>>1, wn = wid&1, lr = l&15, lg = l>>4;
  int mbase = blockIdx.y*64 + wm*32;
  int nblk = blockIdx.x*64;
  bool isX = (nblk < H_N);
  int nbase = nblk + wn*32;
  const u16* WTh = isX? WxTh : WrxTh;
  const u16* WTl = isX? WxTl : WrxTl;
  int nw0 = isX? nbase : (nbase - H_N);
  const float* ar[2]; const u16* brh[2]; const u16* brl[2];
  #pragma unroll
  for(int mt=0;mt<2;mt++){
    int m = mbase + mt*16 + lr;
    ar[mt] = x + ((size_t)(m & (B_N-1))*S_N + (m>>5))*H_N;   // m = t*32 + b
  }
  #pragma unroll
  for(int nt=0;nt<2;nt++){
    brh[nt] = WTh + (size_t)(nw0 + nt*16 + lr)*H_N;
    brl[nt] = WTl + (size_t)(nw0 + nt*16 + lr)*H_N;
  }
  f32x4 zz = {0.f,0.f,0.f,0.f};
  f32x4 acc[2][2] = {{zz,zz},{zz,zz}};
  for(int ks=0;ks<32;ks++){
    int ke = ks*32 + lg*8;
    bf16x8 ah[2], al[2], bh[2], bl[2];
    #pragma unroll
    for(int mt=0;mt<2;mt++) cvt8(ar[mt]+ke, ah[mt], al[mt]);
    #pragma unroll
    for(int nt=0;nt<2;nt++){ bh[nt] = ld8(brh[nt]+ke); bl[nt] = ld8(brl[nt]+ke); }
    #pragma unroll
    for(int mt=0;mt<2;mt++)
      #pragma unroll
      for(int nt=0;nt<2;nt++){
        acc[mt][nt] = MFMA16(ah[mt],bh[nt],acc[mt][nt]);
        acc[mt][nt] = MFMA16(al[mt],bh[nt],acc[mt][nt]);
        acc[mt][nt] = MFMA16(ah[mt],bl[nt],acc[mt][nt]);
      }
  }
  #pragma unroll
  for(int mt=0;mt<2;mt++)
    #pragma unroll
    for(int nt=0;nt<2;nt++){
      int n = nbase + nt*16 + lr;
      #pragma unroll
      for(int i=0;i<4;i++){
        int m = mbase + mt*16 + lg*4 + i;
        size_t idx = (size_t)m*H_N + (isX? n : (n - H_N));
        float v = acc[mt][nt][i];
        if(isX){
          float tv = tanhf(v + b_x[n]);
          u16 h = f2bu(tv);
          xp[idx] = h;
          if(xplo) xplo[idx] = f2bu(tv - bu2f(h));
        }else{
          u16 h = f2bu(v);
          xr[idx] = h;
          if(xrlo) xrlo[idx] = f2bu(v - bu2f(h));
        }
      }
    }
}

// ---------- final: out[b][t][:] = tanh(hall[m=t*32+b][:] @ W_o + b_o) (fp32) --
__global__ __launch_bounds__(256) void k_fin(const u16* __restrict__ hall,
    const u16* __restrict__ WoTh, const u16* __restrict__ WoTl,
    const float* __restrict__ b_o, float* __restrict__ out){
  int tid = threadIdx.x, l = tid&63, wid = tid>>6;
  int wm = wid>>1, wn = wid&1, lr = l&15, lg = l>>4;
  int mbase = blockIdx.y*64 + wm*32;
  int nbase = blockIdx.x*64 + wn*32;
  const u16* ar[2]; const u16* brh[2]; const u16* brl[2];
  #pragma unroll
  for(int mt=0;mt<2;mt++) ar[mt] = hall + (size_t)(mbase + mt*16 + lr)*H_N;
  #pragma unroll
  for(int nt=0;nt<2;nt++){
    brh[nt] = WoTh + (size_t)(nbase + nt*16 + lr)*H_N;
    brl[nt] = WoTl + (size_t)(nbase + nt*16 + lr)*H_N;
  }
  f32x4 zz = {0.f,0.f,0.f,0.f};
  f32x4 acc[2][2] = {{zz,zz},{zz,zz}};
  for(int ks=0;ks<32;ks++){
    int ke = ks*32 + lg*8;
    #pragma unroll
    for(int mt=0;mt<2;mt++){
      bf16x8 a = ld8(ar[mt] + ke);
      #pragma unroll
      for(int nt=0;nt<2;nt++){
        acc[mt][nt] = MFMA16(a, ld8(brh[nt]+ke), acc[mt][nt]);
        acc[mt][nt] = MFMA16(a, ld8(brl[nt]+ke), acc[mt][nt]);
      }
    }
  }
  #pragma unroll
  for(int mt=0;mt<2;mt++)
    #pragma unroll
    for(int nt=0;nt<2;nt++){
      int n = nbase + nt*16 + lr;
      float bo = b_o[n];
      #pragma unroll
      for(int i=0;i<4;i++){
        int m = mbase + mt*16 + lg*4 + i;
        int b = m & (B_N-1), t = m >> 5;
        out[((size_t)b*S_N + t)*H_N + n] = tanhf(acc[mt][nt][i] + bo);
      }
    }
}

// ---------- one recurrence step: 32 blocks x 256 threads (4 waves) -----------
// Block owns pairs p in [bid*16, bid*16+16). Wave kq = tid>>6 is a K-quarter;
// cand uses 3-term split (Wh hi+lo, h hi+lo); r/s use 2-term (W hi, h hi+lo).
__global__ __launch_bounds__(256) void k_step3(
    const u16* __restrict__ hih, const u16* __restrict__ hil,
    u16* __restrict__ hall_t, u16* __restrict__ lon_buf,
    const u16* __restrict__ xp_t, const u16* __restrict__ xplo_t,
    const u16* __restrict__ xr_t, const u16* __restrict__ xrlo_t,
    const u16* __restrict__ WhTh, const u16* __restrict__ WhTl,
    const u16* __restrict__ WrTh, const u16* __restrict__ wsp,
    const float* __restrict__ b_h, const float* __restrict__ b_r,
    const float* __restrict__ b_s,
    const float* __restrict__ mob_a, const float* __restrict__ mob_b,
    const float* __restrict__ mob_c, const float* __restrict__ mob_d,
    float* __restrict__ hf)
{
  __shared__ float Cred[32*84];
  __shared__ float Cs[32*84];
  __shared__ float mobp[16*25];
  __shared__ float bias[64];
  __shared__ float sbar[32];
  __shared__ float bsv[3];
  int tid = threadIdx.x, bid = blockIdx.x;
  int P0 = bid*16;
  int l = tid&63, kq = tid>>6;
  int lr = l&15, lg = l>>4;

  for(int idx=tid; idx<384; idx+=256){
    int j = idx/24, c = idx%24, cyc = c>>3, q = c&7;
    const float* arr = (q<2)? mob_a : (q<4)? mob_b : (q<6)? mob_c : mob_d;
    mobp[j*25 + c] = arr[cyc*H_N + (q&1)*HH_N + P0 + j];
  }
  if(tid < 64){
    int grp = tid>>4, jj = tid&15;
    bias[tid] = ((grp<2)? b_h : b_r)[P0 + jj + ((grp&1)? HH_N : 0)];
  } else if(tid < 67){
    bsv[tid-64] = b_s[tid-64];
  }

  const u16* bhOh = WhTh + (size_t)(P0 + lr)*H_N;
  const u16* bhOl = WhTl + (size_t)(P0 + lr)*H_N;
  const u16* bhPh = WhTh + (size_t)(P0 + HH_N + lr)*H_N;
  const u16* bhPl = WhTl + (size_t)(P0 + HH_N + lr)*H_N;
  const u16* brO  = WrTh + (size_t)(P0 + lr)*H_N;
  const u16* brP  = WrTh + (size_t)(P0 + HH_N + lr)*H_N;
  const u16* wps  = wsp + (size_t)(kq*8)*512 + l*8;
  const u16* a0h  = hih + (size_t)lr*H_N;
  const u16* a1h  = hih + (size_t)(16+lr)*H_N;
  const u16* a0l  = hil + (size_t)lr*H_N;
  const u16* a1l  = hil + (size_t)(16+lr)*H_N;

  f32x4 zz = {0.f,0.f,0.f,0.f};
  f32x4 cO0=zz,cO1=zz,cP0=zz,cP1=zz,rOa=zz,rOb=zz,rPa=zz,rPb=zz,sA=zz,sB=zz;
  #pragma unroll
  for(int i=0;i<8;i++){
    int ke = (kq*8+i)*32 + lg*8;
    bf16x8 ah0 = ld8(a0h+ke), ah1 = ld8(a1h+ke);
    bf16x8 al0 = ld8(a0l+ke), al1 = ld8(a1l+ke);
    bf16x8 fOh = ld8(bhOh+ke), fOl = ld8(bhOl+ke);
    bf16x8 fPh = ld8(bhPh+ke), fPl = ld8(bhPl+ke);
    bf16x8 frO_ = ld8(brO+ke), frP_ = ld8(brP+ke);
    bf16x8 fs   = ld8(wps + i*512);
    cO0 = MFMA16(ah0,fOh,cO0); cO0 = MFMA16(al0,fOh,cO0); cO0 = MFMA16(ah0,fOl,cO0);
    cO1 = MFMA16(ah1,fOh,cO1); cO1 = MFMA16(al1,fOh,cO1); cO1 = MFMA16(ah1,fOl,cO1);
    cP0 = MFMA16(ah0,fPh,cP0); cP0 = MFMA16(al0,fPh,cP0); cP0 = MFMA16(ah0,fPl,cP0);
    cP1 = MFMA16(ah1,fPh,cP1); cP1 = MFMA16(al1,fPh,cP1); cP1 = MFMA16(ah1,fPl,cP1);
    rOa = MFMA16(ah0,frO_,rOa); rOa = MFMA16(al0,frO_,rOa);
    rOb = MFMA16(ah1,frO_,rOb); rOb = MFMA16(al1,frO_,rOb);
    rPa = MFMA16(ah0,frP_,rPa); rPa = MFMA16(al0,frP_,rPa);
    rPb = MFMA16(ah1,frP_,rPb); rPb = MFMA16(al1,frP_,rPb);
    sA  = MFMA16(ah0,fs, sA);  sA  = MFMA16(al0,fs, sA);
    sB  = MFMA16(ah1,fs, sB);  sB  = MFMA16(al1,fs, sB);
  }

  // 4-way K-reduce: kq0->Cred, kq1->Cs write; kq2->Cred, kq3->Cs add; merge
  __syncthreads();
  float* D = (kq&1)? Cs : Cred;
  if(kq < 2){
    #pragma unroll
    for(int i=0;i<4;i++){
      int r0 = (lg*4+i)*84, r1 = (16+lg*4+i)*84;
      D[r0 +      lr] = cO0[i];  D[r1 +      lr] = cO1[i];
      D[r0 + 16 + lr] = cP0[i];  D[r1 + 16 + lr] = cP1[i];
      D[r0 + 32 + lr] = rOa[i];  D[r1 + 32 + lr] = rOb[i];
      D[r0 + 48 + lr] = rPa[i];  D[r1 + 48 + lr] = rPb[i];
      D[r0 + 64 + lr] = sA[i];   D[r1 + 64 + lr] = sB[i];
    }
  }
  __syncthreads();
  if(kq >= 2){
    #pragma unroll
    for(int i=0;i<4;i++){
      int r0 = (lg*4+i)*84, r1 = (16+lg*4+i)*84;
      D[r0 +      lr] += cO0[i];  D[r1 +      lr] += cO1[i];
      D[r0 + 16 + lr] += cP0[i];  D[r1 + 16 + lr] += cP1[i];
      D[r0 + 32 + lr] += rOa[i];  D[r1 + 32 + lr] += rOb[i];
      D[r0 + 48 + lr] += rPa[i];  D[r1 + 48 + lr] += rPb[i];
      D[r0 + 64 + lr] += sA[i];   D[r1 + 64 + lr] += sB[i];
    }
  }
  __syncthreads();
  for(int idx=tid; idx<2560; idx+=256){          // 32 rows x 80 cols
    int r = idx/80, c = idx - r*80;
    Cred[r*84+c] += Cs[r*84+c];
  }
  __syncthreads();

  if(tid < 32){
    float l0 = Cred[tid*84+64] + bsv[0];
    float l1 = Cred[tid*84+65] + bsv[1];
    float l2 = Cred[tid*84+66] + bsv[2];
    float mx = fmaxf(l0, fmaxf(l1,l2));
    float e0 = expf(l0-mx), e1 = expf(l1-mx), e2 = expf(l2-mx);
    sbar[tid] = (e0 + 0.5f*e1 + 0.25f*e2) / (e0+e1+e2);
  }
  __syncthreads();

  // elementwise: each thread owns (row, j) and (row+16, j)
  int j = tid&15, rbase = tid>>4;
  int c0 = P0 + j, c1 = c0 + HH_N;
  #pragma unroll
  for(int rr=0;rr<2;rr++){
    int row = rbase + rr*16;
    size_t i0 = (size_t)row*H_N + c0, i1 = (size_t)row*H_N + c1;
    float xpv0 = bu2f(xp_t[i0]) + bu2f(xplo_t[i0]);
    float xpv1 = bu2f(xp_t[i1]) + bu2f(xplo_t[i1]);
    float xrv0 = bu2f(xr_t[i0]) + bu2f(xrlo_t[i0]);
    float xrv1 = bu2f(xr_t[i1]) + bu2f(xrlo_t[i1]);
    float zo = tanhf(xpv0 + Cred[row*84 + j]      + bias[j]);
    float zp = tanhf(xpv1 + Cred[row*84 + 16 + j] + bias[16+j]);
    float ro = 1.f/(1.f + expf(-(xrv0 + Cred[row*84 + 32 + j] + bias[32+j])));
    float rp = 1.f/(1.f + expf(-(xrv1 + Cred[row*84 + 48 + j] + bias[48+j])));
    const float* mp = &mobp[j*25];
    #pragma unroll
    for(int cy=0;cy<3;cy++){
      float are=mp[cy*8+0], aim=mp[cy*8+1], bre=mp[cy*8+2], bim=mp[cy*8+3];
      float cre=mp[cy*8+4], cim=mp[cy*8+5], dre=mp[cy*8+6], dim_=mp[cy*8+7];
      float nre = are*zo - aim*zp + bre;
      float nim = are*zp + aim*zo + bim;
      float de  = cre*zo - cim*zp + dre;
      float di  = cre*zp + cim*zo + dim_;
      float inv = 1.f/(de*de + di*di + EPS_F);
      float nzo = (nre*de + nim*di)*inv;
      float nzp = (nim*de - nre*di)*inv;
      zo = nzo; zp = nzp;
    }
    float sb = sbar[row];
    ro *= sb; rp *= sb;
    float* hrow = hf + (size_t)row*H_N;
    float ho = hrow[c0], hp2 = hrow[c1];
    float no  = (1.f-ro)*ho + ro*zo;
    float np2 = (1.f-rp)*hp2 + rp*zp;
    hrow[c0] = no; hrow[c1] = np2;
    u16* ht  = hall_t + (size_t)row*H_N;
    u16* lon = lon_buf + (size_t)row*H_N;
    u16 nob = f2bu(no), npb = f2bu(np2);
    ht[c0] = nob; ht[c1] = npb;
    lon[c0] = f2bu(no  - bu2f(nob));
    lon[c1] = f2bu(np2 - bu2f(npb));
  }
}

// ---------- tail: of/pf (fp32) from fp32 master h ----------------------------
__global__ __launch_bounds__(256) void k_tail(const float* __restrict__ hf,
                                              float* __restrict__ out){
  int i = blockIdx.x*256 + threadIdx.x;   // 0..32767
  int b = i >> 10, c = i & 1023;
  float v = hf[(size_t)b*H_N + c];
  size_t base = (size_t)B_N*S_N*H_N;
  size_t idx = (c < HH_N) ? base + (size_t)b*HH_N + c
                          : base + (size_t)B_N*HH_N + (size_t)b*HH_N + (c - HH_N);
  out[idx] = v;
}

// ---------- host -------------------------------------------------------------
// Inputs fp32, output fp32 (proven by round 2's fp32-path pass + npz sizes).
// Base workspace 102.3 MiB < round-2-proven 104.25 MiB floor. Optional xp/xr
// lo-residuals carved only if ws_size allows (else zeroed zhi frame is the lo).
// Aliases: WxT/WrxT hi+lo live in hall frames 0..127 (dead after k_pre);
// WoT hi+lo live in xp (written after steps; xp dead by then).
extern "C" void kernel_launch(void* const* d_in, const int* in_sizes, int n_in,
                              void* d_out, int out_size, void* d_ws, size_t ws_size,
                              hipStream_t stream)
{
  const float* x    = (const float*)d_in[0];
  const float* W_x  = (const float*)d_in[1];
  const float* b_x  = (const float*)d_in[2];
  const float* W_h  = (const float*)d_in[3];
  const float* b_h  = (const float*)d_in[4];
  const float* W_r  = (const float*)d_in[5];
  const float* b_r  = (const float*)d_in[6];
  const float* W_s  = (const float*)d_in[7];
  const float* b_s  = (const float*)d_in[8];
  const float* mob_a= (const float*)d_in[9];
  const float* mob_b= (const float*)d_in[10];
  const float* mob_c= (const float*)d_in[11];
  const float* mob_d= (const float*)d_in[12];
  const float* W_o  = (const float*)d_in[13];
  const float* b_o  = (const float*)d_in[14];
  float* out = (float*)d_out;

  char* ws = (char*)d_ws;
  size_t off = 0;
  auto carve = [&](size_t bytes)->char*{
    char* p = ws + off; off = (off + bytes + 255) & ~(size_t)255; return p;
  };
  float* hf   = (float*)carve((size_t)FRAME*sizeof(float));
  u16*   zhi  = (u16*)carve((size_t)FRAME*sizeof(u16));     // zero h / zero lo frame
  u16*   lob  = (u16*)carve((size_t)2*FRAME*sizeof(u16));
  u16*   WhTh = (u16*)carve((size_t)H_N*H_N*sizeof(u16));
  u16*   WhTl = (u16*)carve((size_t)H_N*H_N*sizeof(u16));
  u16*   WrTh = (u16*)carve((size_t)H_N*H_N*sizeof(u16));
  u16*   wsp  = (u16*)carve((size_t)32*512*sizeof(u16));
  u16*   hall = (u16*)carve((size_t)S_N*FRAME*sizeof(u16));
  u16*   xp   = (u16*)carve((size_t)S_N*FRAME*sizeof(u16));
  u16*   xr   = (u16*)carve((size_t)S_N*FRAME*sizeof(u16));
  size_t base_off = off;
  size_t lo_bytes = (size_t)S_N*FRAME*sizeof(u16);
  bool haslo = (ws_size >= base_off + 2*lo_bytes + 4096);
  u16* xplo = nullptr; u16* xrlo = nullptr;
  if(haslo){
    xplo = (u16*)carve(lo_bytes);
    xrlo = (u16*)carve(lo_bytes);
  }

  const size_t WSZ = (size_t)H_N*H_N;
  u16* WxTh  = hall;             // hall frames 0..127: dead after k_pre
  u16* WxTl  = hall + WSZ;
  u16* WrxTh = hall + 2*WSZ;
  u16* WrxTl = hall + 3*WSZ;
  u16* WoTh  = xp;               // xp dead after step loop
  u16* WoTl  = xp + WSZ;

  // zero whole workspace: any read-before-write yields 0.0, never garbage
  (void)hipMemsetAsync(d_ws, 0, ws_size, stream);

  k_trcvt<<<dim3(32,32),256,0,stream>>>(W_h, WhTh, WhTl);
  k_trcvt<<<dim3(32,32),256,0,stream>>>(W_r + (size_t)H_N*H_N, WrTh, (u16*)nullptr);
  k_trcvt<<<dim3(32,32),256,0,stream>>>(W_x, WxTh, WxTl);
  k_trcvt<<<dim3(32,32),256,0,stream>>>(W_r, WrxTh, WrxTl);
  k_wspack<<<64,256,0,stream>>>(W_s, wsp);
  k_pre<<<dim3(32,256),256,0,stream>>>(x, WxTh, WxTl, WrxTh, WrxTl, b_x,
                                       xp, xplo, xr, xrlo);

  for(int t=0;t<S_N;t++){
    const u16* hih = (t==0)? zhi : (hall + (size_t)(t-1)*FRAME);
    const u16* hil = lob + (size_t)(t&1)*FRAME;
    const u16* xplo_t = haslo ? (xplo + (size_t)t*FRAME) : zhi;
    const u16* xrlo_t = haslo ? (xrlo + (size_t)t*FRAME) : zhi;
    k_step3<<<32,256,0,stream>>>(
        hih, hil,
        hall + (size_t)t*FRAME, lob + (size_t)((t+1)&1)*FRAME,
        xp + (size_t)t*FRAME, xplo_t, xr + (size_t)t*FRAME, xrlo_t,
        WhTh, WhTl, WrTh, wsp, b_h, b_r, b_s,
        mob_a, mob_b, mob_c, mob_d, hf);
  }

  k_trcvt<<<dim3(32,32),256,0,stream>>>(W_o, WoTh, WoTl);   // into dead xp
  k_fin<<<dim3(16,256),256,0,stream>>>(hall, WoTh, WoTl, b_o, out);
  k_tail<<<128,256,0,stream>>>(hf, out);
}

// Round 8
// 7292.780 us; speedup vs baseline: 1.9377x; 1.2749x over previous
//
#include <hip/hip_runtime.h>
#include <math.h>

typedef unsigned short u16;
typedef __attribute__((ext_vector_type(8))) short bf16x8;   // 8 bf16 lanes = 4 VGPR
typedef __attribute__((ext_vector_type(4))) float f32x4;

#define B_N 32
#define S_N 512
#define H_N 1024
#define HH_N 512
#define FRAME (B_N*H_N)        /* 32768 elems */
#define GBLK 32
#define EPS_F 1e-6f

#define MFMA16(a,b,c) __builtin_amdgcn_mfma_f32_16x16x32_bf16((a),(b),(c),0,0,0)

static __device__ __forceinline__ u16 f2bu(float v){      // fp32 -> bf16 bits (RNE)
  union{float f; unsigned u;} x; x.f = v;
  unsigned r = x.u + 0x7FFFu + ((x.u>>16)&1u);
  return (u16)(r>>16);
}
static __device__ __forceinline__ float bu2f(u16 s){
  union{unsigned u; float f;} x; x.u = ((unsigned)s)<<16; return x.f;
}
static __device__ __forceinline__ bf16x8 ld8(const u16* p){
  return *reinterpret_cast<const bf16x8*>(p);
}
static __device__ __forceinline__ void cvt8(const float* p, bf16x8& hi, bf16x8& lo){
  #pragma unroll
  for(int j=0;j<8;j++){
    float v = p[j];
    u16 h = f2bu(v);
    hi[j] = (short)h;
    lo[j] = (short)f2bu(v - bu2f(h));
  }
}

// ---------- fp32 1024x1024 transpose+convert: dst[c][k] = bf16(src[k][c]) ----
__global__ __launch_bounds__(256) void k_trcvt(const float* __restrict__ src,
    u16* __restrict__ dh, u16* __restrict__ dl){
  __shared__ float tile[32][33];
  int c0 = blockIdx.x*32, k0 = blockIdx.y*32;
  int tx = threadIdx.x & 31, ty = threadIdx.x >> 5;
  for(int i=ty;i<32;i+=8) tile[i][tx] = src[(size_t)(k0+i)*H_N + c0 + tx];
  __syncthreads();
  for(int i=ty;i<32;i+=8){
    float v = tile[tx][i];
    u16 h = f2bu(v);
    dh[(size_t)(c0+i)*H_N + k0 + tx] = h;
    if(dl) dl[(size_t)(c0+i)*H_N + k0 + tx] = f2bu(v - bu2f(h));
  }
}

// ---------- W_s padded fragment pack (hi only) --------------------------------
// wsp[ks*512 + l*8 + j] = W_s[k = ks*32+(l>>4)*8+j][col = l&15], col>=3 -> 0
__global__ __launch_bounds__(256) void k_wspack(const float* __restrict__ Ws,
                                                u16* __restrict__ wsp){
  int gid = blockIdx.x*256 + threadIdx.x;        // 0..16383
  int j = gid & 7, l = (gid>>3) & 63, ks = gid >> 9;
  int lr = l & 15, lg = l >> 4;
  int k = ks*32 + lg*8 + j;
  wsp[gid] = (lr < 3) ? f2bu(Ws[k*3 + lr]) : (u16)0;
}

// ---------- precompute: xp = tanh(x@W_x+b_x), xr = x@W_r[:D] -----------------
__global__ __launch_bounds__(256) void k_pre(const float* __restrict__ x,
    const u16* __restrict__ WxTh, const u16* __restrict__ WxTl,
    const u16* __restrict__ WrxTh, const u16* __restrict__ WrxTl,
    const float* __restrict__ b_x,
    u16* __restrict__ xp, u16* __restrict__ xplo,
    u16* __restrict__ xr, u16* __restrict__ xrlo){
  int tid = threadIdx.x, l = tid&63, wid = tid>>6;
  int wm = wid>>1, wn = wid&1, lr = l&15, lg = l>>4;
  int mbase = blockIdx.y*64 + wm*32;
  int nblk = blockIdx.x*64;
  bool isX = (nblk < H_N);
  int nbase = nblk + wn*32;
  const u16* WTh = isX? WxTh : WrxTh;
  const u16* WTl = isX? WxTl : WrxTl;
  int nw0 = isX? nbase : (nbase - H_N);
  const float* ar[2]; const u16* brh[2]; const u16* brl[2];
  #pragma unroll
  for(int mt=0;mt<2;mt++){
    int m = mbase + mt*16 + lr;
    ar[mt] = x + ((size_t)(m & (B_N-1))*S_N + (m>>5))*H_N;   // m = t*32 + b
  }
  #pragma unroll
  for(int nt=0;nt<2;nt++){
    brh[nt] = WTh + (size_t)(nw0 + nt*16 + lr)*H_N;
    brl[nt] = WTl + (size_t)(nw0 + nt*16 + lr)*H_N;
  }
  f32x4 zz = {0.f,0.f,0.f,0.f};
  f32x4 acc[2][2] = {{zz,zz},{zz,zz}};
  for(int ks=0;ks<32;ks++){
    int ke = ks*32 + lg*8;
    bf16x8 ah[2], al[2], bh[2], bl[2];
    #pragma unroll
    for(int mt=0;mt<2;mt++) cvt8(ar[mt]+ke, ah[mt], al[mt]);
    #pragma unroll
    for(int nt=0;nt<2;nt++){ bh[nt] = ld8(brh[nt]+ke); bl[nt] = ld8(brl[nt]+ke); }
    #pragma unroll
    for(int mt=0;mt<2;mt++)
      #pragma unroll
      for(int nt=0;nt<2;nt++){
        acc[mt][nt] = MFMA16(ah[mt],bh[nt],acc[mt][nt]);
        acc[mt][nt] = MFMA16(al[mt],bh[nt],acc[mt][nt]);
        acc[mt][nt] = MFMA16(ah[mt],bl[nt],acc[mt][nt]);
      }
  }
  #pragma unroll
  for(int mt=0;mt<2;mt++)
    #pragma unroll
    for(int nt=0;nt<2;nt++){
      int n = nbase + nt*16 + lr;
      #pragma unroll
      for(int i=0;i<4;i++){
        int m = mbase + mt*16 + lg*4 + i;
        size_t idx = (size_t)m*H_N + (isX? n : (n - H_N));
        float v = acc[mt][nt][i];
        if(isX){
          float tv = tanhf(v + b_x[n]);
          u16 h = f2bu(tv);
          xp[idx] = h;
          if(xplo) xplo[idx] = f2bu(tv - bu2f(h));
        }else{
          u16 h = f2bu(v);
          xr[idx] = h;
          if(xrlo) xrlo[idx] = f2bu(v - bu2f(h));
        }
      }
    }
}

// ---------- final: out[b][t][:] = tanh(hall[m=t*32+b][:] @ W_o + b_o) (fp32) --
__global__ __launch_bounds__(256) void k_fin(const u16* __restrict__ hall,
    const u16* __restrict__ WoTh, const u16* __restrict__ WoTl,
    const float* __restrict__ b_o, float* __restrict__ out){
  int tid = threadIdx.x, l = tid&63, wid = tid>>6;
  int wm = wid>>1, wn = wid&1, lr = l&15, lg = l>>4;
  int mbase = blockIdx.y*64 + wm*32;
  int nbase = blockIdx.x*64 + wn*32;
  const u16* ar[2]; const u16* brh[2]; const u16* brl[2];
  #pragma unroll
  for(int mt=0;mt<2;mt++) ar[mt] = hall + (size_t)(mbase + mt*16 + lr)*H_N;
  #pragma unroll
  for(int nt=0;nt<2;nt++){
    brh[nt] = WoTh + (size_t)(nbase + nt*16 + lr)*H_N;
    brl[nt] = WoTl + (size_t)(nbase + nt*16 + lr)*H_N;
  }
  f32x4 zz = {0.f,0.f,0.f,0.f};
  f32x4 acc[2][2] = {{zz,zz},{zz,zz}};
  for(int ks=0;ks<32;ks++){
    int ke = ks*32 + lg*8;
    #pragma unroll
    for(int mt=0;mt<2;mt++){
      bf16x8 a = ld8(ar[mt] + ke);
      #pragma unroll
      for(int nt=0;nt<2;nt++){
        acc[mt][nt] = MFMA16(a, ld8(brh[nt]+ke), acc[mt][nt]);
        acc[mt][nt] = MFMA16(a, ld8(brl[nt]+ke), acc[mt][nt]);
      }
    }
  }
  #pragma unroll
  for(int mt=0;mt<2;mt++)
    #pragma unroll
    for(int nt=0;nt<2;nt++){
      int n = nbase + nt*16 + lr;
      float bo = b_o[n];
      #pragma unroll
      for(int i=0;i<4;i++){
        int m = mbase + mt*16 + lg*4 + i;
        int b = m & (B_N-1), t = m >> 5;
        out[((size_t)b*S_N + t)*H_N + n] = tanhf(acc[mt][nt][i] + bo);
      }
    }
}

// ---------- persistent recurrence: 32 blocks x 256 threads -------------------
// Identical math to round-7's k_step3, fused over t with a per-step grid
// barrier: release atomic add + acquire spin (agent scope) on cnt[t].
// 32 blocks <= 256 CUs -> guaranteed co-resident.
__global__ __launch_bounds__(256) void k_recur(
    const u16* __restrict__ xp, const u16* __restrict__ xplo0,
    const u16* __restrict__ xr, const u16* __restrict__ xrlo0, int xlostep,
    const u16* __restrict__ WhTh, const u16* __restrict__ WhTl,
    const u16* __restrict__ WrTh, const u16* __restrict__ wsp,
    const float* __restrict__ b_h, const float* __restrict__ b_r,
    const float* __restrict__ b_s,
    const float* __restrict__ mob_a, const float* __restrict__ mob_b,
    const float* __restrict__ mob_c, const float* __restrict__ mob_d,
    const u16* __restrict__ zhi, u16* __restrict__ lob,
    u16* __restrict__ hall, float* __restrict__ hf, int* __restrict__ cnt)
{
  __shared__ float Cred[32*84];
  __shared__ float Cs[32*84];
  __shared__ float mobp[16*25];
  __shared__ float bias[64];
  __shared__ float sbar[32];
  __shared__ float bsv[3];
  int tid = threadIdx.x, bid = blockIdx.x;
  int P0 = bid*16;
  int l = tid&63, kq = tid>>6;
  int lr = l&15, lg = l>>4;

  // one-time staging of per-block params
  for(int idx=tid; idx<384; idx+=256){
    int j = idx/24, c = idx%24, cyc = c>>3, q = c&7;
    const float* arr = (q<2)? mob_a : (q<4)? mob_b : (q<6)? mob_c : mob_d;
    mobp[j*25 + c] = arr[cyc*H_N + (q&1)*HH_N + P0 + j];
  }
  if(tid < 64){
    int grp = tid>>4, jj = tid&15;
    bias[tid] = ((grp<2)? b_h : b_r)[P0 + jj + ((grp&1)? HH_N : 0)];
  } else if(tid < 67){
    bsv[tid-64] = b_s[tid-64];
  }

  const u16* bhOh = WhTh + (size_t)(P0 + lr)*H_N;
  const u16* bhOl = WhTl + (size_t)(P0 + lr)*H_N;
  const u16* bhPh = WhTh + (size_t)(P0 + HH_N + lr)*H_N;
  const u16* bhPl = WhTl + (size_t)(P0 + HH_N + lr)*H_N;
  const u16* brO  = WrTh + (size_t)(P0 + lr)*H_N;
  const u16* brP  = WrTh + (size_t)(P0 + HH_N + lr)*H_N;
  const u16* wps  = wsp + (size_t)(kq*8)*512 + l*8;
  int j = tid&15, rbase = tid>>4;
  int c0 = P0 + j, c1 = c0 + HH_N;

  for(int t=0; t<S_N; t++){
    const u16* hih = (t==0)? zhi : (hall + (size_t)(t-1)*FRAME);
    const u16* hil = lob + (size_t)(t&1)*FRAME;
    const u16* xp_t   = xp + (size_t)t*FRAME;
    const u16* xr_t   = xr + (size_t)t*FRAME;
    const u16* xplo_t = xplo0 + (size_t)t*xlostep;
    const u16* xrlo_t = xrlo0 + (size_t)t*xlostep;
    u16* hall_t  = hall + (size_t)t*FRAME;
    u16* lon_buf = lob + (size_t)((t+1)&1)*FRAME;

    const u16* a0h = hih + (size_t)lr*H_N;
    const u16* a1h = hih + (size_t)(16+lr)*H_N;
    const u16* a0l = hil + (size_t)lr*H_N;
    const u16* a1l = hil + (size_t)(16+lr)*H_N;

    f32x4 zz = {0.f,0.f,0.f,0.f};
    f32x4 cO0=zz,cO1=zz,cP0=zz,cP1=zz,rOa=zz,rOb=zz,rPa=zz,rPb=zz,sA=zz,sB=zz;
    #pragma unroll
    for(int i=0;i<8;i++){
      int ke = (kq*8+i)*32 + lg*8;
      bf16x8 ah0 = ld8(a0h+ke), ah1 = ld8(a1h+ke);
      bf16x8 al0 = ld8(a0l+ke), al1 = ld8(a1l+ke);
      bf16x8 fOh = ld8(bhOh+ke), fOl = ld8(bhOl+ke);
      bf16x8 fPh = ld8(bhPh+ke), fPl = ld8(bhPl+ke);
      bf16x8 frO_ = ld8(brO+ke), frP_ = ld8(brP+ke);
      bf16x8 fs   = ld8(wps + i*512);
      cO0 = MFMA16(ah0,fOh,cO0); cO0 = MFMA16(al0,fOh,cO0); cO0 = MFMA16(ah0,fOl,cO0);
      cO1 = MFMA16(ah1,fOh,cO1); cO1 = MFMA16(al1,fOh,cO1); cO1 = MFMA16(ah1,fOl,cO1);
      cP0 = MFMA16(ah0,fPh,cP0); cP0 = MFMA16(al0,fPh,cP0); cP0 = MFMA16(ah0,fPl,cP0);
      cP1 = MFMA16(ah1,fPh,cP1); cP1 = MFMA16(al1,fPh,cP1); cP1 = MFMA16(ah1,fPl,cP1);
      rOa = MFMA16(ah0,frO_,rOa); rOa = MFMA16(al0,frO_,rOa);
      rOb = MFMA16(ah1,frO_,rOb); rOb = MFMA16(al1,frO_,rOb);
      rPa = MFMA16(ah0,frP_,rPa); rPa = MFMA16(al0,frP_,rPa);
      rPb = MFMA16(ah1,frP_,rPb); rPb = MFMA16(al1,frP_,rPb);
      sA  = MFMA16(ah0,fs, sA);  sA  = MFMA16(al0,fs, sA);
      sB  = MFMA16(ah1,fs, sB);  sB  = MFMA16(al1,fs, sB);
    }

    // 4-way K-reduce: kq0->Cred, kq1->Cs write; kq2->Cred, kq3->Cs add; merge
    __syncthreads();
    float* D = (kq&1)? Cs : Cred;
    if(kq < 2){
      #pragma unroll
      for(int i=0;i<4;i++){
        int r0 = (lg*4+i)*84, r1 = (16+lg*4+i)*84;
        D[r0 +      lr] = cO0[i];  D[r1 +      lr] = cO1[i];
        D[r0 + 16 + lr] = cP0[i];  D[r1 + 16 + lr] = cP1[i];
        D[r0 + 32 + lr] = rOa[i];  D[r1 + 32 + lr] = rOb[i];
        D[r0 + 48 + lr] = rPa[i];  D[r1 + 48 + lr] = rPb[i];
        D[r0 + 64 + lr] = sA[i];   D[r1 + 64 + lr] = sB[i];
      }
    }
    __syncthreads();
    if(kq >= 2){
      #pragma unroll
      for(int i=0;i<4;i++){
        int r0 = (lg*4+i)*84, r1 = (16+lg*4+i)*84;
        D[r0 +      lr] += cO0[i];  D[r1 +      lr] += cO1[i];
        D[r0 + 16 + lr] += cP0[i];  D[r1 + 16 + lr] += cP1[i];
        D[r0 + 32 + lr] += rOa[i];  D[r1 + 32 + lr] += rOb[i];
        D[r0 + 48 + lr] += rPa[i];  D[r1 + 48 + lr] += rPb[i];
        D[r0 + 64 + lr] += sA[i];   D[r1 + 64 + lr] += sB[i];
      }
    }
    __syncthreads();
    for(int idx=tid; idx<2560; idx+=256){          // 32 rows x 80 cols
      int r = idx/80, c = idx - r*80;
      Cred[r*84+c] += Cs[r*84+c];
    }
    __syncthreads();

    if(tid < 32){
      float l0 = Cred[tid*84+64] + bsv[0];
      float l1 = Cred[tid*84+65] + bsv[1];
      float l2 = Cred[tid*84+66] + bsv[2];
      float mx = fmaxf(l0, fmaxf(l1,l2));
      float e0 = expf(l0-mx), e1 = expf(l1-mx), e2 = expf(l2-mx);
      sbar[tid] = (e0 + 0.5f*e1 + 0.25f*e2) / (e0+e1+e2);
    }
    __syncthreads();

    // elementwise: each thread owns (row, j) and (row+16, j)
    #pragma unroll
    for(int rr=0;rr<2;rr++){
      int row = rbase + rr*16;
      size_t i0 = (size_t)row*H_N + c0, i1 = (size_t)row*H_N + c1;
      float xpv0 = bu2f(xp_t[i0]) + bu2f(xplo_t[i0]);
      float xpv1 = bu2f(xp_t[i1]) + bu2f(xplo_t[i1]);
      float xrv0 = bu2f(xr_t[i0]) + bu2f(xrlo_t[i0]);
      float xrv1 = bu2f(xr_t[i1]) + bu2f(xrlo_t[i1]);
      float zo = tanhf(xpv0 + Cred[row*84 + j]      + bias[j]);
      float zp = tanhf(xpv1 + Cred[row*84 + 16 + j] + bias[16+j]);
      float ro = 1.f/(1.f + expf(-(xrv0 + Cred[row*84 + 32 + j] + bias[32+j])));
      float rp = 1.f/(1.f + expf(-(xrv1 + Cred[row*84 + 48 + j] + bias[48+j])));
      const float* mp = &mobp[j*25];
      #pragma unroll
      for(int cy=0;cy<3;cy++){
        float are=mp[cy*8+0], aim=mp[cy*8+1], bre=mp[cy*8+2], bim=mp[cy*8+3];
        float cre=mp[cy*8+4], cim=mp[cy*8+5], dre=mp[cy*8+6], dim_=mp[cy*8+7];
        float nre = are*zo - aim*zp + bre;
        float nim = are*zp + aim*zo + bim;
        float de  = cre*zo - cim*zp + dre;
        float di  = cre*zp + cim*zo + dim_;
        float inv = 1.f/(de*de + di*di + EPS_F);
        float nzo = (nre*de + nim*di)*inv;
        float nzp = (nim*de - nre*di)*inv;
        zo = nzo; zp = nzp;
      }
      float sb = sbar[row];
      ro *= sb; rp *= sb;
      float* hrow = hf + (size_t)row*H_N;
      float ho = hrow[c0], hp2 = hrow[c1];
      float no  = (1.f-ro)*ho + ro*zo;
      float np2 = (1.f-rp)*hp2 + rp*zp;
      hrow[c0] = no; hrow[c1] = np2;
      u16* ht  = hall_t + (size_t)row*H_N;
      u16* lon = lon_buf + (size_t)row*H_N;
      u16 nob = f2bu(no), npb = f2bu(np2);
      ht[c0] = nob; ht[c1] = npb;
      lon[c0] = f2bu(no  - bu2f(nob));
      lon[c1] = f2bu(np2 - bu2f(npb));
    }

    // grid barrier: release add + acquire spin, agent scope, per-step slot
    __syncthreads();        // all waves' stores issued; waitcnt drained at barrier
    if(tid == 0){
      __hip_atomic_fetch_add(&cnt[t], 1, __ATOMIC_ACQ_REL, __HIP_MEMORY_SCOPE_AGENT);
      while(__hip_atomic_load(&cnt[t], __ATOMIC_ACQUIRE, __HIP_MEMORY_SCOPE_AGENT) < GBLK)
        __builtin_amdgcn_s_sleep(1);
    }
    __syncthreads();
  }
}

// ---------- tail: of/pf (fp32) from fp32 master h ----------------------------
__global__ __launch_bounds__(256) void k_tail(const float* __restrict__ hf,
                                              float* __restrict__ out){
  int i = blockIdx.x*256 + threadIdx.x;   // 0..32767
  int b = i >> 10, c = i & 1023;
  float v = hf[(size_t)b*H_N + c];
  size_t base = (size_t)B_N*S_N*H_N;
  size_t idx = (c < HH_N) ? base + (size_t)b*HH_N + c
                          : base + (size_t)B_N*HH_N + (size_t)b*HH_N + (c - HH_N);
  out[idx] = v;
}

// ---------- host -------------------------------------------------------------
// Inputs fp32, output fp32. Base workspace ~102.3 MiB (+4KB cnt). Optional
// xp/xr lo-residuals carved only if ws_size allows (else zeroed zhi frame).
// Aliases: WxT/WrxT hi+lo live in hall frames 0..127 (dead after k_pre);
// WoT hi+lo live in xp (written after recurrence; xp dead by then).
extern "C" void kernel_launch(void* const* d_in, const int* in_sizes, int n_in,
                              void* d_out, int out_size, void* d_ws, size_t ws_size,
                              hipStream_t stream)
{
  const float* x    = (const float*)d_in[0];
  const float* W_x  = (const float*)d_in[1];
  const float* b_x  = (const float*)d_in[2];
  const float* W_h  = (const float*)d_in[3];
  const float* b_h  = (const float*)d_in[4];
  const float* W_r  = (const float*)d_in[5];
  const float* b_r  = (const float*)d_in[6];
  const float* W_s  = (const float*)d_in[7];
  const float* b_s  = (const float*)d_in[8];
  const float* mob_a= (const float*)d_in[9];
  const float* mob_b= (const float*)d_in[10];
  const float* mob_c= (const float*)d_in[11];
  const float* mob_d= (const float*)d_in[12];
  const float* W_o  = (const float*)d_in[13];
  const float* b_o  = (const float*)d_in[14];
  float* out = (float*)d_out;

  char* ws = (char*)d_ws;
  size_t off = 0;
  auto carve = [&](size_t bytes)->char*{
    char* p = ws + off; off = (off + bytes + 255) & ~(size_t)255; return p;
  };
  int*   cnt  = (int*)carve(4096);                          // 512 step slots
  float* hf   = (float*)carve((size_t)FRAME*sizeof(float));
  u16*   zhi  = (u16*)carve((size_t)FRAME*sizeof(u16));     // zero h / zero lo frame
  u16*   lob  = (u16*)carve((size_t)2*FRAME*sizeof(u16));
  u16*   WhTh = (u16*)carve((size_t)H_N*H_N*sizeof(u16));
  u16*   WhTl = (u16*)carve((size_t)H_N*H_N*sizeof(u16));
  u16*   WrTh = (u16*)carve((size_t)H_N*H_N*sizeof(u16));
  u16*   wsp  = (u16*)carve((size_t)32*512*sizeof(u16));
  u16*   hall = (u16*)carve((size_t)S_N*FRAME*sizeof(u16));
  u16*   xp   = (u16*)carve((size_t)S_N*FRAME*sizeof(u16));
  u16*   xr   = (u16*)carve((size_t)S_N*FRAME*sizeof(u16));
  size_t base_off = off;
  size_t lo_bytes = (size_t)S_N*FRAME*sizeof(u16);
  bool haslo = (ws_size >= base_off + 2*lo_bytes + 4096);
  u16* xplo = nullptr; u16* xrlo = nullptr;
  if(haslo){
    xplo = (u16*)carve(lo_bytes);
    xrlo = (u16*)carve(lo_bytes);
  }

  const size_t WSZ = (size_t)H_N*H_N;
  u16* WxTh  = hall;             // hall frames 0..127: dead after k_pre
  u16* WxTl  = hall + WSZ;
  u16* WrxTh = hall + 2*WSZ;
  u16* WrxTl = hall + 3*WSZ;
  u16* WoTh  = xp;               // xp dead after recurrence
  u16* WoTl  = xp + WSZ;

  // zero whole workspace: cnt slots + zhi/lob/hf deterministic each call
  (void)hipMemsetAsync(d_ws, 0, ws_size, stream);

  k_trcvt<<<dim3(32,32),256,0,stream>>>(W_h, WhTh, WhTl);
  k_trcvt<<<dim3(32,32),256,0,stream>>>(W_r + (size_t)H_N*H_N, WrTh, (u16*)nullptr);
  k_trcvt<<<dim3(32,32),256,0,stream>>>(W_x, WxTh, WxTl);
  k_trcvt<<<dim3(32,32),256,0,stream>>>(W_r, WrxTh, WrxTl);
  k_wspack<<<64,256,0,stream>>>(W_s, wsp);
  k_pre<<<dim3(32,256),256,0,stream>>>(x, WxTh, WxTl, WrxTh, WrxTl, b_x,
                                       xp, xplo, xr, xrlo);

  k_recur<<<GBLK,256,0,stream>>>(
      xp, haslo ? xplo : zhi, xr, haslo ? xrlo : zhi, haslo ? FRAME : 0,
      WhTh, WhTl, WrTh, wsp, b_h, b_r, b_s,
      mob_a, mob_b, mob_c, mob_d, zhi, lob, hall, hf, cnt);

  k_trcvt<<<dim3(32,32),256,0,stream>>>(W_o, WoTh, WoTl);   // into dead xp
  k_fin<<<dim3(16,256),256,0,stream>>>(hall, WoTh, WoTl, b_o, out);
  k_tail<<<128,256,0,stream>>>(hf, out);
}

// Round 9
// 7036.008 us; speedup vs baseline: 2.0084x; 1.0365x over previous
//
#include <hip/hip_runtime.h>
#include <math.h>

typedef unsigned short u16;
typedef __attribute__((ext_vector_type(8))) short bf16x8;   // 8 bf16 lanes = 4 VGPR
typedef __attribute__((ext_vector_type(4))) float f32x4;

#define B_N 32
#define S_N 512
#define H_N 1024
#define HH_N 512
#define FRAME (B_N*H_N)        /* 32768 elems */
#define GBLK 32
#define EPS_F 1e-6f

#define MFMA16(a,b,c) __builtin_amdgcn_mfma_f32_16x16x32_bf16((a),(b),(c),0,0,0)

static __device__ __forceinline__ u16 f2bu(float v){      // fp32 -> bf16 bits (RNE)
  union{float f; unsigned u;} x; x.f = v;
  unsigned r = x.u + 0x7FFFu + ((x.u>>16)&1u);
  return (u16)(r>>16);
}
static __device__ __forceinline__ float bu2f(u16 s){
  union{unsigned u; float f;} x; x.u = ((unsigned)s)<<16; return x.f;
}
static __device__ __forceinline__ bf16x8 ld8(const u16* p){
  return *reinterpret_cast<const bf16x8*>(p);
}
static __device__ __forceinline__ void cvt8(const float* p, bf16x8& hi, bf16x8& lo){
  #pragma unroll
  for(int j=0;j<8;j++){
    float v = p[j];
    u16 h = f2bu(v);
    hi[j] = (short)h;
    lo[j] = (short)f2bu(v - bu2f(h));
  }
}

// ---------- fp32 1024x1024 transpose+convert: dst[c][k] = bf16(src[k][c]) ----
__global__ __launch_bounds__(256) void k_trcvt(const float* __restrict__ src,
    u16* __restrict__ dh, u16* __restrict__ dl){
  __shared__ float tile[32][33];
  int c0 = blockIdx.x*32, k0 = blockIdx.y*32;
  int tx = threadIdx.x & 31, ty = threadIdx.x >> 5;
  for(int i=ty;i<32;i+=8) tile[i][tx] = src[(size_t)(k0+i)*H_N + c0 + tx];
  __syncthreads();
  for(int i=ty;i<32;i+=8){
    float v = tile[tx][i];
    u16 h = f2bu(v);
    dh[(size_t)(c0+i)*H_N + k0 + tx] = h;
    if(dl) dl[(size_t)(c0+i)*H_N + k0 + tx] = f2bu(v - bu2f(h));
  }
}

// ---------- W_s padded fragment pack (hi only) --------------------------------
__global__ __launch_bounds__(256) void k_wspack(const float* __restrict__ Ws,
                                                u16* __restrict__ wsp){
  int gid = blockIdx.x*256 + threadIdx.x;        // 0..16383
  int j = gid & 7, l = (gid>>3) & 63, ks = gid >> 9;
  int lr = l & 15, lg = l >> 4;
  int k = ks*32 + lg*8 + j;
  wsp[gid] = (lr < 3) ? f2bu(Ws[k*3 + lr]) : (u16)0;
}

// ---------- precompute: xp = tanh(x@W_x+b_x), xr = x@W_r[:D] -----------------
__global__ __launch_bounds__(256) void k_pre(const float* __restrict__ x,
    const u16* __restrict__ WxTh, const u16* __restrict__ WxTl,
    const u16* __restrict__ WrxTh, const u16* __restrict__ WrxTl,
    const float* __restrict__ b_x,
    u16* __restrict__ xp, u16* __restrict__ xplo,
    u16* __restrict__ xr, u16* __restrict__ xrlo){
  int tid = threadIdx.x, l = tid&63, wid = tid>>6;
  int wm = wid>>1, wn = wid&1, lr = l&15, lg = l>>4;
  int mbase = blockIdx.y*64 + wm*32;
  int nblk = blockIdx.x*64;
  bool isX = (nblk < H_N);
  int nbase = nblk + wn*32;
  const u16* WTh = isX? WxTh : WrxTh;
  const u16* WTl = isX? WxTl : WrxTl;
  int nw0 = isX? nbase : (nbase - H_N);
  const float* ar[2]; const u16* brh[2]; const u16* brl[2];
  #pragma unroll
  for(int mt=0;mt<2;mt++){
    int m = mbase + mt*16 + lr;
    ar[mt] = x + ((size_t)(m & (B_N-1))*S_N + (m>>5))*H_N;   // m = t*32 + b
  }
  #pragma unroll
  for(int nt=0;nt<2;nt++){
    brh[nt] = WTh + (size_t)(nw0 + nt*16 + lr)*H_N;
    brl[nt] = WTl + (size_t)(nw0 + nt*16 + lr)*H_N;
  }
  f32x4 zz = {0.f,0.f,0.f,0.f};
  f32x4 acc[2][2] = {{zz,zz},{zz,zz}};
  for(int ks=0;ks<32;ks++){
    int ke = ks*32 + lg*8;
    bf16x8 ah[2], al[2], bh[2], bl[2];
    #pragma unroll
    for(int mt=0;mt<2;mt++) cvt8(ar[mt]+ke, ah[mt], al[mt]);
    #pragma unroll
    for(int nt=0;nt<2;nt++){ bh[nt] = ld8(brh[nt]+ke); bl[nt] = ld8(brl[nt]+ke); }
    #pragma unroll
    for(int mt=0;mt<2;mt++)
      #pragma unroll
      for(int nt=0;nt<2;nt++){
        acc[mt][nt] = MFMA16(ah[mt],bh[nt],acc[mt][nt]);
        acc[mt][nt] = MFMA16(al[mt],bh[nt],acc[mt][nt]);
        acc[mt][nt] = MFMA16(ah[mt],bl[nt],acc[mt][nt]);
      }
  }
  #pragma unroll
  for(int mt=0;mt<2;mt++)
    #pragma unroll
    for(int nt=0;nt<2;nt++){
      int n = nbase + nt*16 + lr;
      #pragma unroll
      for(int i=0;i<4;i++){
        int m = mbase + mt*16 + lg*4 + i;
        size_t idx = (size_t)m*H_N + (isX? n : (n - H_N));
        float v = acc[mt][nt][i];
        if(isX){
          float tv = tanhf(v + b_x[n]);
          u16 h = f2bu(tv);
          xp[idx] = h;
          if(xplo) xplo[idx] = f2bu(tv - bu2f(h));
        }else{
          u16 h = f2bu(v);
          xr[idx] = h;
          if(xrlo) xrlo[idx] = f2bu(v - bu2f(h));
        }
      }
    }
}

// ---------- final: out[b][t][:] = tanh(hall[m=t*32+b][:] @ W_o + b_o) (fp32) --
__global__ __launch_bounds__(256) void k_fin(const u16* __restrict__ hall,
    const u16* __restrict__ WoTh, const u16* __restrict__ WoTl,
    const float* __restrict__ b_o, float* __restrict__ out){
  int tid = threadIdx.x, l = tid&63, wid = tid>>6;
  int wm = wid>>1, wn = wid&1, lr = l&15, lg = l>>4;
  int mbase = blockIdx.y*64 + wm*32;
  int nbase = blockIdx.x*64 + wn*32;
  const u16* ar[2]; const u16* brh[2]; const u16* brl[2];
  #pragma unroll
  for(int mt=0;mt<2;mt++) ar[mt] = hall + (size_t)(mbase + mt*16 + lr)*H_N;
  #pragma unroll
  for(int nt=0;nt<2;nt++){
    brh[nt] = WoTh + (size_t)(nbase + nt*16 + lr)*H_N;
    brl[nt] = WoTl + (size_t)(nbase + nt*16 + lr)*H_N;
  }
  f32x4 zz = {0.f,0.f,0.f,0.f};
  f32x4 acc[2][2] = {{zz,zz},{zz,zz}};
  for(int ks=0;ks<32;ks++){
    int ke = ks*32 + lg*8;
    #pragma unroll
    for(int mt=0;mt<2;mt++){
      bf16x8 a = ld8(ar[mt] + ke);
      #pragma unroll
      for(int nt=0;nt<2;nt++){
        acc[mt][nt] = MFMA16(a, ld8(brh[nt]+ke), acc[mt][nt]);
        acc[mt][nt] = MFMA16(a, ld8(brl[nt]+ke), acc[mt][nt]);
      }
    }
  }
  #pragma unroll
  for(int mt=0;mt<2;mt++)
    #pragma unroll
    for(int nt=0;nt<2;nt++){
      int n = nbase + nt*16 + lr;
      float bo = b_o[n];
      #pragma unroll
      for(int i=0;i<4;i++){
        int m = mbase + mt*16 + lg*4 + i;
        int b = m & (B_N-1), t = m >> 5;
        out[((size_t)b*S_N + t)*H_N + n] = tanhf(acc[mt][nt][i] + bo);
      }
    }
}

// ---------- persistent recurrence: 32 blocks x 256 threads -------------------
// Grid barrier = store/parallel-poll flags: block bid release-stores
// arr[bid*32] = t+1; wave-0 lanes poll all 32 flags in parallel (acquire).
// No RMW, no shared-line contention. 32 blocks <= 256 CUs -> co-resident.
__global__ __launch_bounds__(256) void k_recur(
    const u16* __restrict__ xp, const u16* __restrict__ xplo0,
    const u16* __restrict__ xr, const u16* __restrict__ xrlo0, int xlostep,
    const u16* __restrict__ WhTh, const u16* __restrict__ WhTl,
    const u16* __restrict__ WrTh, const u16* __restrict__ wsp,
    const float* __restrict__ b_h, const float* __restrict__ b_r,
    const float* __restrict__ b_s,
    const float* __restrict__ mob_a, const float* __restrict__ mob_b,
    const float* __restrict__ mob_c, const float* __restrict__ mob_d,
    const u16* __restrict__ zhi, u16* __restrict__ lob,
    u16* __restrict__ hall, float* __restrict__ hf, int* __restrict__ arr)
{
  __shared__ float Cred[32*84];
  __shared__ float Cs[32*84];
  __shared__ float mobp[16*25];
  __shared__ float bias[64];
  __shared__ float sbar[32];
  __shared__ float bsv[3];
  int tid = threadIdx.x, bid = blockIdx.x;
  int P0 = bid*16;
  int l = tid&63, kq = tid>>6;
  int lr = l&15, lg = l>>4;

  // one-time staging of per-block params
  for(int idx=tid; idx<384; idx+=256){
    int j = idx/24, c = idx%24, cyc = c>>3, q = c&7;
    const float* arrp = (q<2)? mob_a : (q<4)? mob_b : (q<6)? mob_c : mob_d;
    mobp[j*25 + c] = arrp[cyc*H_N + (q&1)*HH_N + P0 + j];
  }
  if(tid < 64){
    int grp = tid>>4, jj = tid&15;
    bias[tid] = ((grp<2)? b_h : b_r)[P0 + jj + ((grp&1)? HH_N : 0)];
  } else if(tid < 67){
    bsv[tid-64] = b_s[tid-64];
  }

  const u16* bhOh = WhTh + (size_t)(P0 + lr)*H_N;
  const u16* bhOl = WhTl + (size_t)(P0 + lr)*H_N;
  const u16* bhPh = WhTh + (size_t)(P0 + HH_N + lr)*H_N;
  const u16* bhPl = WhTl + (size_t)(P0 + HH_N + lr)*H_N;
  const u16* brO  = WrTh + (size_t)(P0 + lr)*H_N;
  const u16* brP  = WrTh + (size_t)(P0 + HH_N + lr)*H_N;
  const u16* wps  = wsp + (size_t)(kq*8)*512 + l*8;
  int j = tid&15, rbase = tid>>4;
  int c0 = P0 + j, c1 = c0 + HH_N;

  for(int t=0; t<S_N; t++){
    const u16* hih = (t==0)? zhi : (hall + (size_t)(t-1)*FRAME);
    const u16* hil = lob + (size_t)(t&1)*FRAME;
    const u16* xp_t   = xp + (size_t)t*FRAME;
    const u16* xr_t   = xr + (size_t)t*FRAME;
    const u16* xplo_t = xplo0 + (size_t)t*xlostep;
    const u16* xrlo_t = xrlo0 + (size_t)t*xlostep;
    u16* hall_t  = hall + (size_t)t*FRAME;
    u16* lon_buf = lob + (size_t)((t+1)&1)*FRAME;

    const u16* a0h = hih + (size_t)lr*H_N;
    const u16* a1h = hih + (size_t)(16+lr)*H_N;
    const u16* a0l = hil + (size_t)lr*H_N;
    const u16* a1l = hil + (size_t)(16+lr)*H_N;

    f32x4 zz = {0.f,0.f,0.f,0.f};
    f32x4 cO0=zz,cO1=zz,cP0=zz,cP1=zz,rOa=zz,rOb=zz,rPa=zz,rPb=zz,sA=zz,sB=zz;
    #pragma unroll
    for(int i=0;i<8;i++){
      int ke = (kq*8+i)*32 + lg*8;
      bf16x8 ah0 = ld8(a0h+ke), ah1 = ld8(a1h+ke);
      bf16x8 al0 = ld8(a0l+ke), al1 = ld8(a1l+ke);
      bf16x8 fOh = ld8(bhOh+ke), fOl = ld8(bhOl+ke);
      bf16x8 fPh = ld8(bhPh+ke), fPl = ld8(bhPl+ke);
      bf16x8 frO_ = ld8(brO+ke), frP_ = ld8(brP+ke);
      bf16x8 fs   = ld8(wps + i*512);
      cO0 = MFMA16(ah0,fOh,cO0); cO0 = MFMA16(al0,fOh,cO0); cO0 = MFMA16(ah0,fOl,cO0);
      cO1 = MFMA16(ah1,fOh,cO1); cO1 = MFMA16(al1,fOh,cO1); cO1 = MFMA16(ah1,fOl,cO1);
      cP0 = MFMA16(ah0,fPh,cP0); cP0 = MFMA16(al0,fPh,cP0); cP0 = MFMA16(ah0,fPl,cP0);
      cP1 = MFMA16(ah1,fPh,cP1); cP1 = MFMA16(al1,fPh,cP1); cP1 = MFMA16(ah1,fPl,cP1);
      rOa = MFMA16(ah0,frO_,rOa); rOa = MFMA16(al0,frO_,rOa);
      rOb = MFMA16(ah1,frO_,rOb); rOb = MFMA16(al1,frO_,rOb);
      rPa = MFMA16(ah0,frP_,rPa); rPa = MFMA16(al0,frP_,rPa);
      rPb = MFMA16(ah1,frP_,rPb); rPb = MFMA16(al1,frP_,rPb);
      sA  = MFMA16(ah0,fs, sA);  sA  = MFMA16(al0,fs, sA);
      sB  = MFMA16(ah1,fs, sB);  sB  = MFMA16(al1,fs, sB);
    }

    // 4-way K-reduce: kq0->Cred, kq1->Cs write; kq2->Cred, kq3->Cs add; merge
    __syncthreads();
    float* D = (kq&1)? Cs : Cred;
    if(kq < 2){
      #pragma unroll
      for(int i=0;i<4;i++){
        int r0 = (lg*4+i)*84, r1 = (16+lg*4+i)*84;
        D[r0 +      lr] = cO0[i];  D[r1 +      lr] = cO1[i];
        D[r0 + 16 + lr] = cP0[i];  D[r1 + 16 + lr] = cP1[i];
        D[r0 + 32 + lr] = rOa[i];  D[r1 + 32 + lr] = rOb[i];
        D[r0 + 48 + lr] = rPa[i];  D[r1 + 48 + lr] = rPb[i];
        D[r0 + 64 + lr] = sA[i];   D[r1 + 64 + lr] = sB[i];
      }
    }
    __syncthreads();
    if(kq >= 2){
      #pragma unroll
      for(int i=0;i<4;i++){
        int r0 = (lg*4+i)*84, r1 = (16+lg*4+i)*84;
        D[r0 +      lr] += cO0[i];  D[r1 +      lr] += cO1[i];
        D[r0 + 16 + lr] += cP0[i];  D[r1 + 16 + lr] += cP1[i];
        D[r0 + 32 + lr] += rOa[i];  D[r1 + 32 + lr] += rOb[i];
        D[r0 + 48 + lr] += rPa[i];  D[r1 + 48 + lr] += rPb[i];
        D[r0 + 64 + lr] += sA[i];   D[r1 + 64 + lr] += sB[i];
      }
    }
    __syncthreads();
    for(int idx=tid; idx<2560; idx+=256){          // 32 rows x 80 cols
      int r = idx/80, c = idx - r*80;
      Cred[r*84+c] += Cs[r*84+c];
    }
    __syncthreads();

    if(tid < 32){
      float l0 = Cred[tid*84+64] + bsv[0];
      float l1 = Cred[tid*84+65] + bsv[1];
      float l2 = Cred[tid*84+66] + bsv[2];
      float mx = fmaxf(l0, fmaxf(l1,l2));
      float e0 = expf(l0-mx), e1 = expf(l1-mx), e2 = expf(l2-mx);
      sbar[tid] = (e0 + 0.5f*e1 + 0.25f*e2) / (e0+e1+e2);
    }
    __syncthreads();

    // elementwise: each thread owns (row, j) and (row+16, j)
    #pragma unroll
    for(int rr=0;rr<2;rr++){
      int row = rbase + rr*16;
      size_t i0 = (size_t)row*H_N + c0, i1 = (size_t)row*H_N + c1;
      float xpv0 = bu2f(xp_t[i0]) + bu2f(xplo_t[i0]);
      float xpv1 = bu2f(xp_t[i1]) + bu2f(xplo_t[i1]);
      float xrv0 = bu2f(xr_t[i0]) + bu2f(xrlo_t[i0]);
      float xrv1 = bu2f(xr_t[i1]) + bu2f(xrlo_t[i1]);
      float zo = tanhf(xpv0 + Cred[row*84 + j]      + bias[j]);
      float zp = tanhf(xpv1 + Cred[row*84 + 16 + j] + bias[16+j]);
      float ro = 1.f/(1.f + expf(-(xrv0 + Cred[row*84 + 32 + j] + bias[32+j])));
      float rp = 1.f/(1.f + expf(-(xrv1 + Cred[row*84 + 48 + j] + bias[48+j])));
      const float* mp = &mobp[j*25];
      #pragma unroll
      for(int cy=0;cy<3;cy++){
        float are=mp[cy*8+0], aim=mp[cy*8+1], bre=mp[cy*8+2], bim=mp[cy*8+3];
        float cre=mp[cy*8+4], cim=mp[cy*8+5], dre=mp[cy*8+6], dim_=mp[cy*8+7];
        float nre = are*zo - aim*zp + bre;
        float nim = are*zp + aim*zo + bim;
        float de  = cre*zo - cim*zp + dre;
        float di  = cre*zp + cim*zo + dim_;
        float inv = 1.f/(de*de + di*di + EPS_F);
        float nzo = (nre*de + nim*di)*inv;
        float nzp = (nim*de - nre*di)*inv;
        zo = nzo; zp = nzp;
      }
      float sb = sbar[row];
      ro *= sb; rp *= sb;
      float* hrow = hf + (size_t)row*H_N;
      float ho = hrow[c0], hp2 = hrow[c1];
      float no  = (1.f-ro)*ho + ro*zo;
      float np2 = (1.f-rp)*hp2 + rp*zp;
      hrow[c0] = no; hrow[c1] = np2;
      u16* ht  = hall_t + (size_t)row*H_N;
      u16* lon = lon_buf + (size_t)row*H_N;
      u16 nob = f2bu(no), npb = f2bu(np2);
      ht[c0] = nob; ht[c1] = npb;
      lon[c0] = f2bu(no  - bu2f(nob));
      lon[c1] = f2bu(np2 - bu2f(npb));
    }

    // grid barrier: per-block flag store (release) + wave-parallel poll (acquire)
    __syncthreads();        // all waves' stores drained before the release
    if(tid == 0)
      __hip_atomic_store(&arr[bid<<5], t+1, __ATOMIC_RELEASE, __HIP_MEMORY_SCOPE_AGENT);
    if(tid < GBLK){
      while(__hip_atomic_load(&arr[tid<<5], __ATOMIC_ACQUIRE, __HIP_MEMORY_SCOPE_AGENT) <= t)
        __builtin_amdgcn_s_sleep(1);
    }
    __syncthreads();
  }
}

// ---------- tail: of/pf (fp32) from fp32 master h ----------------------------
__global__ __launch_bounds__(256) void k_tail(const float* __restrict__ hf,
                                              float* __restrict__ out){
  int i = blockIdx.x*256 + threadIdx.x;   // 0..32767
  int b = i >> 10, c = i & 1023;
  float v = hf[(size_t)b*H_N + c];
  size_t base = (size_t)B_N*S_N*H_N;
  size_t idx = (c < HH_N) ? base + (size_t)b*HH_N + c
                          : base + (size_t)B_N*HH_N + (size_t)b*HH_N + (c - HH_N);
  out[idx] = v;
}

// ---------- host -------------------------------------------------------------
// Inputs fp32, output fp32. Only the header (flags|hf|zhi|lob, ~330 KB) needs
// zeroing each call; all other regions are written before read.
extern "C" void kernel_launch(void* const* d_in, const int* in_sizes, int n_in,
                              void* d_out, int out_size, void* d_ws, size_t ws_size,
                              hipStream_t stream)
{
  const float* x    = (const float*)d_in[0];
  const float* W_x  = (const float*)d_in[1];
  const float* b_x  = (const float*)d_in[2];
  const float* W_h  = (const float*)d_in[3];
  const float* b_h  = (const float*)d_in[4];
  const float* W_r  = (const float*)d_in[5];
  const float* b_r  = (const float*)d_in[6];
  const float* W_s  = (const float*)d_in[7];
  const float* b_s  = (const float*)d_in[8];
  const float* mob_a= (const float*)d_in[9];
  const float* mob_b= (const float*)d_in[10];
  const float* mob_c= (const float*)d_in[11];
  const float* mob_d= (const float*)d_in[12];
  const float* W_o  = (const float*)d_in[13];
  const float* b_o  = (const float*)d_in[14];
  float* out = (float*)d_out;

  char* ws = (char*)d_ws;
  size_t off = 0;
  auto carve = [&](size_t bytes)->char*{
    char* p = ws + off; off = (off + bytes + 255) & ~(size_t)255; return p;
  };
  int*   arr  = (int*)carve(4096);                          // 32 flags, 128B apart
  float* hf   = (float*)carve((size_t)FRAME*sizeof(float));
  u16*   zhi  = (u16*)carve((size_t)FRAME*sizeof(u16));     // zero h / zero lo frame
  u16*   lob  = (u16*)carve((size_t)2*FRAME*sizeof(u16));
  size_t hdr_bytes = off;                                   // zeroed region
  u16*   WhTh = (u16*)carve((size_t)H_N*H_N*sizeof(u16));
  u16*   WhTl = (u16*)carve((size_t)H_N*H_N*sizeof(u16));
  u16*   WrTh = (u16*)carve((size_t)H_N*H_N*sizeof(u16));
  u16*   wsp  = (u16*)carve((size_t)32*512*sizeof(u16));
  u16*   hall = (u16*)carve((size_t)S_N*FRAME*sizeof(u16));
  u16*   xp   = (u16*)carve((size_t)S_N*FRAME*sizeof(u16));
  u16*   xr   = (u16*)carve((size_t)S_N*FRAME*sizeof(u16));
  size_t base_off = off;
  size_t lo_bytes = (size_t)S_N*FRAME*sizeof(u16);
  bool haslo = (ws_size >= base_off + 2*lo_bytes + 4096);
  u16* xplo = nullptr; u16* xrlo = nullptr;
  if(haslo){
    xplo = (u16*)carve(lo_bytes);
    xrlo = (u16*)carve(lo_bytes);
  }

  const size_t WSZ = (size_t)H_N*H_N;
  u16* WxTh  = hall;             // hall frames 0..127: dead after k_pre
  u16* WxTl  = hall + WSZ;
  u16* WrxTh = hall + 2*WSZ;
  u16* WrxTl = hall + 3*WSZ;
  u16* WoTh  = xp;               // xp dead after recurrence
  u16* WoTl  = xp + WSZ;

  // zero only the header: flags + hf + zhi + lob (deterministic each call)
  (void)hipMemsetAsync(d_ws, 0, hdr_bytes, stream);

  k_trcvt<<<dim3(32,32),256,0,stream>>>(W_h, WhTh, WhTl);
  k_trcvt<<<dim3(32,32),256,0,stream>>>(W_r + (size_t)H_N*H_N, WrTh, (u16*)nullptr);
  k_trcvt<<<dim3(32,32),256,0,stream>>>(W_x, WxTh, WxTl);
  k_trcvt<<<dim3(32,32),256,0,stream>>>(W_r, WrxTh, WrxTl);
  k_wspack<<<64,256,0,stream>>>(W_s, wsp);
  k_pre<<<dim3(32,256),256,0,stream>>>(x, WxTh, WxTl, WrxTh, WrxTl, b_x,
                                       xp, xplo, xr, xrlo);

  k_recur<<<GBLK,256,0,stream>>>(
      xp, haslo ? xplo : zhi, xr, haslo ? xrlo : zhi, haslo ? FRAME : 0,
      WhTh, WhTl, WrTh, wsp, b_h, b_r, b_s,
      mob_a, mob_b, mob_c, mob_d, zhi, lob, hall, hf, arr);

  k_trcvt<<<dim3(32,32),256,0,stream>>>(W_o, WoTh, WoTl);   // into dead xp
  k_fin<<<dim3(16,256),256,0,stream>>>(hall, WoTh, WoTl, b_o, out);
  k_tail<<<128,256,0,stream>>>(hf, out);
}

// Round 10
// 5686.761 us; speedup vs baseline: 2.4849x; 1.2373x over previous
//
#include <hip/hip_runtime.h>
#include <math.h>

typedef unsigned short u16;
typedef unsigned int u32;
typedef __attribute__((ext_vector_type(8))) short bf16x8;   // 8 bf16 lanes = 4 VGPR
typedef __attribute__((ext_vector_type(4))) float f32x4;

#define B_N 32
#define S_N 512
#define H_N 1024
#define HH_N 512
#define FRAME (B_N*H_N)        /* 32768 elems */
#define GBLK 32
#define EPS_F 1e-6f

#define MFMA16(a,b,c) __builtin_amdgcn_mfma_f32_16x16x32_bf16((a),(b),(c),0,0,0)
#define ATOM_ST(p,v) __hip_atomic_store((p),(v),__ATOMIC_RELAXED,__HIP_MEMORY_SCOPE_AGENT)

static __device__ __forceinline__ u16 f2bu(float v){      // fp32 -> bf16 bits (RNE)
  union{float f; unsigned u;} x; x.f = v;
  unsigned r = x.u + 0x7FFFu + ((x.u>>16)&1u);
  return (u16)(r>>16);
}
static __device__ __forceinline__ float bu2f(u16 s){
  union{unsigned u; float f;} x; x.u = ((unsigned)s)<<16; return x.f;
}
static __device__ __forceinline__ bf16x8 ld8(const u16* p){
  return *reinterpret_cast<const bf16x8*>(p);
}
static __device__ __forceinline__ void cvt8(const float* p, bf16x8& hi, bf16x8& lo){
  #pragma unroll
  for(int j=0;j<8;j++){
    float v = p[j];
    u16 h = f2bu(v);
    hi[j] = (short)h;
    lo[j] = (short)f2bu(v - bu2f(h));
  }
}

// ---------- fp32 1024x1024 transpose+convert: dst[c][k] = bf16(src[k][c]) ----
__global__ __launch_bounds__(256) void k_trcvt(const float* __restrict__ src,
    u16* __restrict__ dh, u16* __restrict__ dl){
  __shared__ float tile[32][33];
  int c0 = blockIdx.x*32, k0 = blockIdx.y*32;
  int tx = threadIdx.x & 31, ty = threadIdx.x >> 5;
  for(int i=ty;i<32;i+=8) tile[i][tx] = src[(size_t)(k0+i)*H_N + c0 + tx];
  __syncthreads();
  for(int i=ty;i<32;i+=8){
    float v = tile[tx][i];
    u16 h = f2bu(v);
    dh[(size_t)(c0+i)*H_N + k0 + tx] = h;
    if(dl) dl[(size_t)(c0+i)*H_N + k0 + tx] = f2bu(v - bu2f(h));
  }
}

// ---------- W_s padded fragment pack (hi only) --------------------------------
__global__ __launch_bounds__(256) void k_wspack(const float* __restrict__ Ws,
                                                u16* __restrict__ wsp){
  int gid = blockIdx.x*256 + threadIdx.x;        // 0..16383
  int j = gid & 7, l = (gid>>3) & 63, ks = gid >> 9;
  int lr = l & 15, lg = l >> 4;
  int k = ks*32 + lg*8 + j;
  wsp[gid] = (lr < 3) ? f2bu(Ws[k*3 + lr]) : (u16)0;
}

// ---------- precompute: xp = tanh(x@W_x+b_x), xr = x@W_r[:D] -----------------
__global__ __launch_bounds__(256) void k_pre(const float* __restrict__ x,
    const u16* __restrict__ WxTh, const u16* __restrict__ WxTl,
    const u16* __restrict__ WrxTh, const u16* __restrict__ WrxTl,
    const float* __restrict__ b_x,
    u16* __restrict__ xp, u16* __restrict__ xplo,
    u16* __restrict__ xr, u16* __restrict__ xrlo){
  int tid = threadIdx.x, l = tid&63, wid = tid>>6;
  int wm = wid>>1, wn = wid&1, lr = l&15, lg = l>>4;
  int mbase = blockIdx.y*64 + wm*32;
  int nblk = blockIdx.x*64;
  bool isX = (nblk < H_N);
  int nbase = nblk + wn*32;
  const u16* WTh = isX? WxTh : WrxTh;
  const u16* WTl = isX? WxTl : WrxTl;
  int nw0 = isX? nbase : (nbase - H_N);
  const float* ar[2]; const u16* brh[2]; const u16* brl[2];
  #pragma unroll
  for(int mt=0;mt<2;mt++){
    int m = mbase + mt*16 + lr;
    ar[mt] = x + ((size_t)(m & (B_N-1))*S_N + (m>>5))*H_N;   // m = t*32 + b
  }
  #pragma unroll
  for(int nt=0;nt<2;nt++){
    brh[nt] = WTh + (size_t)(nw0 + nt*16 + lr)*H_N;
    brl[nt] = WTl + (size_t)(nw0 + nt*16 + lr)*H_N;
  }
  f32x4 zz = {0.f,0.f,0.f,0.f};
  f32x4 acc[2][2] = {{zz,zz},{zz,zz}};
  for(int ks=0;ks<32;ks++){
    int ke = ks*32 + lg*8;
    bf16x8 ah[2], al[2], bh[2], bl[2];
    #pragma unroll
    for(int mt=0;mt<2;mt++) cvt8(ar[mt]+ke, ah[mt], al[mt]);
    #pragma unroll
    for(int nt=0;nt<2;nt++){ bh[nt] = ld8(brh[nt]+ke); bl[nt] = ld8(brl[nt]+ke); }
    #pragma unroll
    for(int mt=0;mt<2;mt++)
      #pragma unroll
      for(int nt=0;nt<2;nt++){
        acc[mt][nt] = MFMA16(ah[mt],bh[nt],acc[mt][nt]);
        acc[mt][nt] = MFMA16(al[mt],bh[nt],acc[mt][nt]);
        acc[mt][nt] = MFMA16(ah[mt],bl[nt],acc[mt][nt]);
      }
  }
  #pragma unroll
  for(int mt=0;mt<2;mt++)
    #pragma unroll
    for(int nt=0;nt<2;nt++){
      int n = nbase + nt*16 + lr;
      #pragma unroll
      for(int i=0;i<4;i++){
        int m = mbase + mt*16 + lg*4 + i;
        size_t idx = (size_t)m*H_N + (isX? n : (n - H_N));
        float v = acc[mt][nt][i];
        if(isX){
          float tv = tanhf(v + b_x[n]);
          u16 h = f2bu(tv);
          xp[idx] = h;
          if(xplo) xplo[idx] = f2bu(tv - bu2f(h));
        }else{
          u16 h = f2bu(v);
          xr[idx] = h;
          if(xrlo) xrlo[idx] = f2bu(v - bu2f(h));
        }
      }
    }
}

// ---------- final: out[b][t][:] = tanh(h(t,b,:) @ W_o + b_o) (fp32) ----------
// hall is BLOCK-MAJOR: hall[t][owner][row][c], c in [0,32):
//   c<16 -> global col owner*16+c ; c>=16 -> owner*16 + 512 + (c-16)
__global__ __launch_bounds__(256) void k_fin(const u16* __restrict__ hall,
    const u16* __restrict__ WoTh, const u16* __restrict__ WoTl,
    const float* __restrict__ b_o, float* __restrict__ out){
  int tid = threadIdx.x, l = tid&63, wid = tid>>6;
  int wm = wid>>1, wn = wid&1, lr = l&15, lg = l>>4;
  int mbase = blockIdx.y*64 + wm*32;
  int nbase = blockIdx.x*64 + wn*32;
  size_t arowB[2]; const u16* brh[2]; const u16* brl[2];
  #pragma unroll
  for(int mt=0;mt<2;mt++){
    int m = mbase + mt*16 + lr;                       // m = t*32 + b
    arowB[mt] = (size_t)(m>>5)*FRAME + (size_t)(m&31)*32;
  }
  #pragma unroll
  for(int nt=0;nt<2;nt++){
    brh[nt] = WoTh + (size_t)(nbase + nt*16 + lr)*H_N;
    brl[nt] = WoTl + (size_t)(nbase + nt*16 + lr)*H_N;
  }
  int lgadd = (lg>>1)*1024 + (lg&1)*8;
  f32x4 zz = {0.f,0.f,0.f,0.f};
  f32x4 acc[2][2] = {{zz,zz},{zz,zz}};
  for(int ks=0;ks<32;ks++){
    int ke = ks*32 + lg*8;
    int abase = (2*(ks&15))*1024 + lgadd + ((ks>=16)?16:0);
    #pragma unroll
    for(int mt=0;mt<2;mt++){
      bf16x8 a = ld8(hall + arowB[mt] + abase);
      #pragma unroll
      for(int nt=0;nt<2;nt++){
        acc[mt][nt] = MFMA16(a, ld8(brh[nt]+ke), acc[mt][nt]);
        acc[mt][nt] = MFMA16(a, ld8(brl[nt]+ke), acc[mt][nt]);
      }
    }
  }
  #pragma unroll
  for(int mt=0;mt<2;mt++)
    #pragma unroll
    for(int nt=0;nt<2;nt++){
      int n = nbase + nt*16 + lr;
      float bo = b_o[n];
      #pragma unroll
      for(int i=0;i<4;i++){
        int m = mbase + mt*16 + lg*4 + i;
        int b = m & (B_N-1), t = m >> 5;
        out[((size_t)b*S_N + t)*H_N + n] = tanhf(acc[mt][nt][i] + bo);
      }
    }
}

// ---------- persistent recurrence: 32 blocks x 256 threads -------------------
// h exchange (hall hi + lob lo) is block-major, written with relaxed
// agent-scope u32 atomic stores (write-through) -> release flag has ~no dirty
// L2 to write back. Barrier = round-9 release store + acquire parallel poll.
// fp32 master h lives in LDS; written to global hf once at the end.
__global__ __launch_bounds__(256) void k_recur(
    const u16* __restrict__ xp, const u16* __restrict__ xplo0,
    const u16* __restrict__ xr, const u16* __restrict__ xrlo0, int xlostep,
    const u16* __restrict__ WhTh, const u16* __restrict__ WhTl,
    const u16* __restrict__ WrTh, const u16* __restrict__ wsp,
    const float* __restrict__ b_h, const float* __restrict__ b_r,
    const float* __restrict__ b_s,
    const float* __restrict__ mob_a, const float* __restrict__ mob_b,
    const float* __restrict__ mob_c, const float* __restrict__ mob_d,
    const u16* __restrict__ zhi, u16* __restrict__ lob,
    u16* __restrict__ hall, float* __restrict__ hf, int* __restrict__ arr)
{
  __shared__ float Cred[32*84];
  __shared__ float Cs[32*84];
  __shared__ float mobp[16*25];
  __shared__ float bias[64];
  __shared__ float sbar[32];
  __shared__ float bsv[3];
  __shared__ float hfL[32][33];        // fp32 master h, block-private
  int tid = threadIdx.x, bid = blockIdx.x;
  int P0 = bid*16;
  int l = tid&63, kq = tid>>6;
  int lr = l&15, lg = l>>4;

  // one-time staging of per-block params
  for(int idx=tid; idx<384; idx+=256){
    int j = idx/24, c = idx%24, cyc = c>>3, q = c&7;
    const float* arrp = (q<2)? mob_a : (q<4)? mob_b : (q<6)? mob_c : mob_d;
    mobp[j*25 + c] = arrp[cyc*H_N + (q&1)*HH_N + P0 + j];
  }
  if(tid < 64){
    int grp = tid>>4, jj = tid&15;
    bias[tid] = ((grp<2)? b_h : b_r)[P0 + jj + ((grp&1)? HH_N : 0)];
  } else if(tid < 67){
    bsv[tid-64] = b_s[tid-64];
  }
  for(int idx=tid; idx<32*33; idx+=256) (&hfL[0][0])[idx] = 0.f;

  const u16* bhOh = WhTh + (size_t)(P0 + lr)*H_N;
  const u16* bhOl = WhTl + (size_t)(P0 + lr)*H_N;
  const u16* bhPh = WhTh + (size_t)(P0 + HH_N + lr)*H_N;
  const u16* bhPl = WhTl + (size_t)(P0 + HH_N + lr)*H_N;
  const u16* brO  = WrTh + (size_t)(P0 + lr)*H_N;
  const u16* brP  = WrTh + (size_t)(P0 + HH_N + lr)*H_N;
  const u16* wps  = wsp + (size_t)(kq*8)*512 + l*8;
  // block-major A addressing: addr = owner*1024 + row*32 + coff (+16 if k>=512)
  int lgadd = (lg>>1)*1024 + (lg&1)*8 + ((kq>=2)?16:0);
  int row0t = lr*32, row1t = (16+lr)*32;
  // elementwise mapping: thread = (row, pair-duo)
  int erow = tid>>3, ejj = (tid&7)*2;          // pairs ejj, ejj+1
  size_t ei0 = (size_t)erow*H_N + P0 + ejj;    // row-major xp/xr index (cols c0,c0+1)
  size_t ei1 = ei0 + HH_N;

  __syncthreads();

  for(int t=0; t<S_N; t++){
    const u16* hihB = (t==0)? zhi : (hall + (size_t)(t-1)*FRAME);
    const u16* hilB = lob + (size_t)(t&1)*FRAME;
    const u16* xp_t   = xp + (size_t)t*FRAME;
    const u16* xr_t   = xr + (size_t)t*FRAME;
    const u16* xplo_t = xplo0 + (size_t)t*xlostep;
    const u16* xrlo_t = xrlo0 + (size_t)t*xlostep;

    // prefetch elementwise inputs early (independent of h)
    u32 pxpL = *(const u32*)(xp_t   + ei0);
    u32 pxpH = *(const u32*)(xp_t   + ei1);
    u32 ploL = *(const u32*)(xplo_t + ei0);
    u32 ploH = *(const u32*)(xplo_t + ei1);
    u32 pxrL = *(const u32*)(xr_t   + ei0);
    u32 pxrH = *(const u32*)(xr_t   + ei1);
    u32 prlL = *(const u32*)(xrlo_t + ei0);
    u32 prlH = *(const u32*)(xrlo_t + ei1);

    f32x4 zz = {0.f,0.f,0.f,0.f};
    f32x4 cO0=zz,cO1=zz,cP0=zz,cP1=zz,rOa=zz,rOb=zz,rPa=zz,rPb=zz,sA=zz,sB=zz;
    #pragma unroll
    for(int i=0;i<8;i++){
      int ke = (kq*8+i)*32 + lg*8;                    // row-major W offset
      int abase = (2*((kq&1)*8+i))*1024 + lgadd;      // block-major h offset
      bf16x8 ah0 = ld8(hihB + abase + row0t);
      bf16x8 ah1 = ld8(hihB + abase + row1t);
      bf16x8 al0 = ld8(hilB + abase + row0t);
      bf16x8 al1 = ld8(hilB + abase + row1t);
      bf16x8 fOh = ld8(bhOh+ke), fOl = ld8(bhOl+ke);
      bf16x8 fPh = ld8(bhPh+ke), fPl = ld8(bhPl+ke);
      bf16x8 frO_ = ld8(brO+ke), frP_ = ld8(brP+ke);
      bf16x8 fs   = ld8(wps + i*512);
      cO0 = MFMA16(ah0,fOh,cO0); cO0 = MFMA16(al0,fOh,cO0); cO0 = MFMA16(ah0,fOl,cO0);
      cO1 = MFMA16(ah1,fOh,cO1); cO1 = MFMA16(al1,fOh,cO1); cO1 = MFMA16(ah1,fOl,cO1);
      cP0 = MFMA16(ah0,fPh,cP0); cP0 = MFMA16(al0,fPh,cP0); cP0 = MFMA16(ah0,fPl,cP0);
      cP1 = MFMA16(ah1,fPh,cP1); cP1 = MFMA16(al1,fPh,cP1); cP1 = MFMA16(ah1,fPl,cP1);
      rOa = MFMA16(ah0,frO_,rOa); rOa = MFMA16(al0,frO_,rOa);
      rOb = MFMA16(ah1,frO_,rOb); rOb = MFMA16(al1,frO_,rOb);
      rPa = MFMA16(ah0,frP_,rPa); rPa = MFMA16(al0,frP_,rPa);
      rPb = MFMA16(ah1,frP_,rPb); rPb = MFMA16(al1,frP_,rPb);
      sA  = MFMA16(ah0,fs, sA);  sA  = MFMA16(al0,fs, sA);
      sB  = MFMA16(ah1,fs, sB);  sB  = MFMA16(al1,fs, sB);
    }

    // 4-way K-reduce: kq0->Cred, kq1->Cs write; kq2->Cred, kq3->Cs add; merge
    __syncthreads();
    float* D = (kq&1)? Cs : Cred;
    if(kq < 2){
      #pragma unroll
      for(int i=0;i<4;i++){
        int r0 = (lg*4+i)*84, r1 = (16+lg*4+i)*84;
        D[r0 +      lr] = cO0[i];  D[r1 +      lr] = cO1[i];
        D[r0 + 16 + lr] = cP0[i];  D[r1 + 16 + lr] = cP1[i];
        D[r0 + 32 + lr] = rOa[i];  D[r1 + 32 + lr] = rOb[i];
        D[r0 + 48 + lr] = rPa[i];  D[r1 + 48 + lr] = rPb[i];
        D[r0 + 64 + lr] = sA[i];   D[r1 + 64 + lr] = sB[i];
      }
    }
    __syncthreads();
    if(kq >= 2){
      #pragma unroll
      for(int i=0;i<4;i++){
        int r0 = (lg*4+i)*84, r1 = (16+lg*4+i)*84;
        D[r0 +      lr] += cO0[i];  D[r1 +      lr] += cO1[i];
        D[r0 + 16 + lr] += cP0[i];  D[r1 + 16 + lr] += cP1[i];
        D[r0 + 32 + lr] += rOa[i];  D[r1 + 32 + lr] += rOb[i];
        D[r0 + 48 + lr] += rPa[i];  D[r1 + 48 + lr] += rPb[i];
        D[r0 + 64 + lr] += sA[i];   D[r1 + 64 + lr] += sB[i];
      }
    }
    __syncthreads();
    for(int idx=tid; idx<2560; idx+=256){          // 32 rows x 80 cols
      int r = idx/80, c = idx - r*80;
      Cred[r*84+c] += Cs[r*84+c];
    }
    __syncthreads();

    if(tid < 32){
      float l0 = Cred[tid*84+64] + bsv[0];
      float l1 = Cred[tid*84+65] + bsv[1];
      float l2 = Cred[tid*84+66] + bsv[2];
      float mx = fmaxf(l0, fmaxf(l1,l2));
      float e0 = expf(l0-mx), e1 = expf(l1-mx), e2 = expf(l2-mx);
      sbar[tid] = (e0 + 0.5f*e1 + 0.25f*e2) / (e0+e1+e2);
    }
    __syncthreads();

    // elementwise: thread owns (erow, pairs ejj & ejj+1)
    {
      float sb = sbar[erow];
      u16 nob[2], npb[2], loO[2], loP[2];
      #pragma unroll
      for(int d=0; d<2; d++){
        int j = ejj + d;
        float xpv0 = bu2f((u16)(pxpL>>(16*d))) + bu2f((u16)(ploL>>(16*d)));
        float xpv1 = bu2f((u16)(pxpH>>(16*d))) + bu2f((u16)(ploH>>(16*d)));
        float xrv0 = bu2f((u16)(pxrL>>(16*d))) + bu2f((u16)(prlL>>(16*d)));
        float xrv1 = bu2f((u16)(pxrH>>(16*d))) + bu2f((u16)(prlH>>(16*d)));
        float zo = tanhf(xpv0 + Cred[erow*84 + j]      + bias[j]);
        float zp = tanhf(xpv1 + Cred[erow*84 + 16 + j] + bias[16+j]);
        float ro = 1.f/(1.f + expf(-(xrv0 + Cred[erow*84 + 32 + j] + bias[32+j])));
        float rp = 1.f/(1.f + expf(-(xrv1 + Cred[erow*84 + 48 + j] + bias[48+j])));
        const float* mp = &mobp[j*25];
        #pragma unroll
        for(int cy=0;cy<3;cy++){
          float are=mp[cy*8+0], aim=mp[cy*8+1], bre=mp[cy*8+2], bim=mp[cy*8+3];
          float cre=mp[cy*8+4], cim=mp[cy*8+5], dre=mp[cy*8+6], dim_=mp[cy*8+7];
          float nre = are*zo - aim*zp + bre;
          float nim = are*zp + aim*zo + bim;
          float de  = cre*zo - cim*zp + dre;
          float di  = cre*zp + cim*zo + dim_;
          float inv = 1.f/(de*de + di*di + EPS_F);
          float nzo = (nre*de + nim*di)*inv;
          float nzp = (nim*de - nre*di)*inv;
          zo = nzo; zp = nzp;
        }
        ro *= sb; rp *= sb;
        float ho = hfL[erow][j], hp2 = hfL[erow][16+j];
        float no  = (1.f-ro)*ho + ro*zo;
        float np2 = (1.f-rp)*hp2 + rp*zp;
        hfL[erow][j] = no; hfL[erow][16+j] = np2;
        nob[d] = f2bu(no);  npb[d] = f2bu(np2);
        loO[d] = f2bu(no  - bu2f(nob[d]));
        loP[d] = f2bu(np2 - bu2f(npb[d]));
      }
      // block-major contiguous write-through stores (4x u32)
      size_t bb = (size_t)bid*1024 + (size_t)erow*32 + ejj;
      u16* hallT = hall + (size_t)t*FRAME;
      u16* lonT  = lob + (size_t)((t+1)&1)*FRAME;
      ATOM_ST((u32*)(hallT + bb),      (u32)nob[0] | ((u32)nob[1]<<16));
      ATOM_ST((u32*)(hallT + bb + 16), (u32)npb[0] | ((u32)npb[1]<<16));
      ATOM_ST((u32*)(lonT  + bb),      (u32)loO[0] | ((u32)loO[1]<<16));
      ATOM_ST((u32*)(lonT  + bb + 16), (u32)loP[0] | ((u32)loP[1]<<16));
    }

    // grid barrier: per-block flag store (release) + wave-parallel poll (acquire)
    __syncthreads();        // drain all waves' stores before the release
    if(tid == 0)
      __hip_atomic_store(&arr[bid<<5], t+1, __ATOMIC_RELEASE, __HIP_MEMORY_SCOPE_AGENT);
    if(tid < GBLK){
      while(__hip_atomic_load(&arr[tid<<5], __ATOMIC_ACQUIRE, __HIP_MEMORY_SCOPE_AGENT) <= t)
        __builtin_amdgcn_s_sleep(1);
    }
    __syncthreads();
  }

  // write fp32 master h out for k_tail
  for(int idx=tid; idx<1024; idx+=256){
    int r = idx>>5, c = idx&31;
    int g = (c<16)? (P0+c) : (P0 + HH_N + (c-16));
    hf[(size_t)r*H_N + g] = hfL[r][c];
  }
}

// ---------- tail: of/pf (fp32) from fp32 master h ----------------------------
__global__ __launch_bounds__(256) void k_tail(const float* __restrict__ hf,
                                              float* __restrict__ out){
  int i = blockIdx.x*256 + threadIdx.x;   // 0..32767
  int b = i >> 10, c = i & 1023;
  float v = hf[(size_t)b*H_N + c];
  size_t base = (size_t)B_N*S_N*H_N;
  size_t idx = (c < HH_N) ? base + (size_t)b*HH_N + c
                          : base + (size_t)B_N*HH_N + (size_t)b*HH_N + (c - HH_N);
  out[idx] = v;
}

// ---------- host -------------------------------------------------------------
extern "C" void kernel_launch(void* const* d_in, const int* in_sizes, int n_in,
                              void* d_out, int out_size, void* d_ws, size_t ws_size,
                              hipStream_t stream)
{
  const float* x    = (const float*)d_in[0];
  const float* W_x  = (const float*)d_in[1];
  const float* b_x  = (const float*)d_in[2];
  const float* W_h  = (const float*)d_in[3];
  const float* b_h  = (const float*)d_in[4];
  const float* W_r  = (const float*)d_in[5];
  const float* b_r  = (const float*)d_in[6];
  const float* W_s  = (const float*)d_in[7];
  const float* b_s  = (const float*)d_in[8];
  const float* mob_a= (const float*)d_in[9];
  const float* mob_b= (const float*)d_in[10];
  const float* mob_c= (const float*)d_in[11];
  const float* mob_d= (const float*)d_in[12];
  const float* W_o  = (const float*)d_in[13];
  const float* b_o  = (const float*)d_in[14];
  float* out = (float*)d_out;

  char* ws = (char*)d_ws;
  size_t off = 0;
  auto carve = [&](size_t bytes)->char*{
    char* p = ws + off; off = (off + bytes + 255) & ~(size_t)255; return p;
  };
  int*   arr  = (int*)carve(4096);                          // 32 flags, 128B apart
  float* hf   = (float*)carve((size_t)FRAME*sizeof(float));
  u16*   zhi  = (u16*)carve((size_t)FRAME*sizeof(u16));     // zero h / zero lo frame
  u16*   lob  = (u16*)carve((size_t)2*FRAME*sizeof(u16));
  size_t hdr_bytes = off;                                   // zeroed region
  u16*   WhTh = (u16*)carve((size_t)H_N*H_N*sizeof(u16));
  u16*   WhTl = (u16*)carve((size_t)H_N*H_N*sizeof(u16));
  u16*   WrTh = (u16*)carve((size_t)H_N*H_N*sizeof(u16));
  u16*   wsp  = (u16*)carve((size_t)32*512*sizeof(u16));
  u16*   hall = (u16*)carve((size_t)S_N*FRAME*sizeof(u16));
  u16*   xp   = (u16*)carve((size_t)S_N*FRAME*sizeof(u16));
  u16*   xr   = (u16*)carve((size_t)S_N*FRAME*sizeof(u16));
  size_t base_off = off;
  size_t lo_bytes = (size_t)S_N*FRAME*sizeof(u16);
  bool haslo = (ws_size >= base_off + 2*lo_bytes + 4096);
  u16* xplo = nullptr; u16* xrlo = nullptr;
  if(haslo){
    xplo = (u16*)carve(lo_bytes);
    xrlo = (u16*)carve(lo_bytes);
  }

  const size_t WSZ = (size_t)H_N*H_N;
  u16* WxTh  = hall;             // hall frames 0..127: dead after k_pre
  u16* WxTl  = hall + WSZ;
  u16* WrxTh = hall + 2*WSZ;
  u16* WrxTl = hall + 3*WSZ;
  u16* WoTh  = xp;               // xp dead after recurrence
  u16* WoTl  = xp + WSZ;

  (void)hipMemsetAsync(d_ws, 0, hdr_bytes, stream);

  k_trcvt<<<dim3(32,32),256,0,stream>>>(W_h, WhTh, WhTl);
  k_trcvt<<<dim3(32,32),256,0,stream>>>(W_r + (size_t)H_N*H_N, WrTh, (u16*)nullptr);
  k_trcvt<<<dim3(32,32),256,0,stream>>>(W_x, WxTh, WxTl);
  k_trcvt<<<dim3(32,32),256,0,stream>>>(W_r, WrxTh, WrxTl);
  k_wspack<<<64,256,0,stream>>>(W_s, wsp);
  k_pre<<<dim3(32,256),256,0,stream>>>(x, WxTh, WxTl, WrxTh, WrxTl, b_x,
                                       xp, xplo, xr, xrlo);

  k_recur<<<GBLK,256,0,stream>>>(
      xp, haslo ? xplo : zhi, xr, haslo ? xrlo : zhi, haslo ? FRAME : 0,
      WhTh, WhTl, WrTh, wsp, b_h, b_r, b_s,
      mob_a, mob_b, mob_c, mob_d, zhi, lob, hall, hf, arr);

  k_trcvt<<<dim3(32,32),256,0,stream>>>(W_o, WoTh, WoTl);   // into dead xp
  k_fin<<<dim3(16,256),256,0,stream>>>(hall, WoTh, WoTl, b_o, out);
  k_tail<<<128,256,0,stream>>>(hf, out);
}